// Round 2
// baseline (1259.159 us; speedup 1.0000x reference)
//
#include <hip/hip_runtime.h>

typedef __attribute__((ext_vector_type(8))) short short8;
typedef __attribute__((ext_vector_type(4))) float f32x4;
typedef __attribute__((ext_vector_type(4))) unsigned short u16x4;
typedef unsigned short u16;

#define D_DIM 1024

__device__ __forceinline__ u16 f2bf(float f) {
  unsigned u = __builtin_bit_cast(unsigned, f);
  u += 0x7fffu + ((u >> 16) & 1u);
  return (u16)(u >> 16);
}
__device__ __forceinline__ float bf2f(u16 b) {
  return __builtin_bit_cast(float, ((unsigned)b) << 16);
}
// tanh-approx gelu matching jax.nn.gelu(approximate=True), hand-rolled exp2
__device__ __forceinline__ float gelu_f(float x) {
  float i = 0.7978845608028654f * (x + 0.044715f * x * x * x);
  float ex = __builtin_amdgcn_exp2f(i * 2.885390081777927f);  // e^{2i}
  float th = 1.0f - 2.0f * __builtin_amdgcn_rcpf(ex + 1.0f);
  return 0.5f * x * (1.0f + th);
}

__device__ __forceinline__ f32x4 mfma16(short8 a, short8 b, f32x4 c) {
  return __builtin_amdgcn_mfma_f32_16x16x32_bf16(a, b, c, 0, 0, 0);
}

__device__ __forceinline__ void glds16(const void* g, void* l) {
  __builtin_amdgcn_global_load_lds(
      (const __attribute__((address_space(1))) void*)g,
      (__attribute__((address_space(3))) void*)l, 16, 0, 0);
}

// Split fp32 W[K][N] (one layer) into bf16 hi/lo, transposed to [N][K].
__global__ __launch_bounds__(256) void prep_w_kernel(
    const float* __restrict__ W, u16* __restrict__ Wth, u16* __restrict__ Wtl) {
  __shared__ float tile[64][65];
  const int t = threadIdx.x;
  const int k0 = blockIdx.x * 64, n0 = blockIdx.y * 64;
#pragma unroll
  for (int j = 0; j < 16; ++j) {
    int idx = t + 256 * j;
    int r = idx >> 6, c = idx & 63;
    tile[r][c] = W[(size_t)(k0 + r) * D_DIM + (n0 + c)];
  }
  __syncthreads();
#pragma unroll
  for (int j = 0; j < 16; ++j) {
    int idx = t + 256 * j;
    int r = idx >> 6, c = idx & 63;
    float f = tile[c][r];
    u16 hb = f2bf(f);
    u16 lb = f2bf(f - bf2f(hb));
    size_t oidx = (size_t)(n0 + r) * D_DIM + (k0 + c);
    Wth[oidx] = hb;
    Wtl[oidx] = lb;
  }
}

// Split fp32 x into bf16 hi/lo planes.
__global__ __launch_bounds__(256) void prep_x_kernel(
    const float* __restrict__ x, u16* __restrict__ xh, u16* __restrict__ xl) {
  size_t i = ((size_t)blockIdx.x * 256 + threadIdx.x) * 4;
  const float4 v = *(const float4*)(x + i);
  const float fv[4] = {v.x, v.y, v.z, v.w};
  u16x4 h4, l4;
#pragma unroll
  for (int c = 0; c < 4; ++c) {
    u16 hb = f2bf(fv[c]);
    h4[c] = hb;
    l4[c] = f2bf(fv[c] - bf2f(hb));
  }
  *(u16x4*)(xh + i) = h4;
  *(u16x4*)(xl + i) = l4;
}

// H' = gelu(H*W + b); also writes zpart[nb][tok] = sum over this block's 128
// cols of H'*halt_w. A,B pre-split bf16 planes, staged via global_load_lds.
__global__ __launch_bounds__(256) void gemm_act_kernel(
    const u16* __restrict__ Ah, const u16* __restrict__ Al,
    const u16* __restrict__ Bh, const u16* __restrict__ Bl,
    const float* __restrict__ bias, const float* __restrict__ halt_w,
    u16* __restrict__ Hh, u16* __restrict__ Hl, float* __restrict__ zpart,
    int M) {
  __shared__ u16 stage[4][4][128][8];  // [plane][kg][row][8] = 32 KiB
  __shared__ float zs[128];
  const int t = threadIdx.x;
  // XCD-chunked bijective swizzle (nwg = 1024, % 8 == 0)
  const int nwg = gridDim.x * gridDim.y;
  const int bid = blockIdx.y * gridDim.x + blockIdx.x;
  const int wg = (bid & 7) * (nwg >> 3) + (bid >> 3);
  const int bn0 = (wg & 7) * 128;
  const int bm0 = (wg >> 3) * 128;
  const int lane = t & 63, wid = t >> 6;
  const int wr = wid >> 1, wc = wid & 1;
  const int g = lane >> 4, r16 = lane & 15;

  // wave `wid` stages plane `wid`
  const u16* splane = (wid == 0) ? Ah : (wid == 1) ? Al : (wid == 2) ? Bh : Bl;
  const int srow0 = (wid < 2) ? bm0 : bn0;
  const u16* sp0 = splane + (size_t)(srow0 + lane) * D_DIM;
  const u16* sp1 = sp0 + (size_t)64 * D_DIM;

  f32x4 acc[4][4];
#pragma unroll
  for (int i = 0; i < 4; ++i)
#pragma unroll
    for (int j = 0; j < 4; ++j) acc[i][j] = (f32x4)0.0f;

  for (int k0 = 0; k0 < D_DIM; k0 += 32) {
#pragma unroll
    for (int kg = 0; kg < 4; ++kg) {
      glds16(sp0 + k0 + kg * 8, &stage[wid][kg][0][0]);
      glds16(sp1 + k0 + kg * 8, &stage[wid][kg][64][0]);
    }
    __syncthreads();
    short8 afh[4], afl[4], bfh[4], bfl[4];
#pragma unroll
    for (int i = 0; i < 4; ++i) {
      const int ar = wr * 64 + i * 16 + r16;
      afh[i] = *(const short8*)&stage[0][g][ar][0];
      afl[i] = *(const short8*)&stage[1][g][ar][0];
      const int bc = wc * 64 + i * 16 + r16;
      bfh[i] = *(const short8*)&stage[2][g][bc][0];
      bfl[i] = *(const short8*)&stage[3][g][bc][0];
    }
#pragma unroll
    for (int mi = 0; mi < 4; ++mi)
#pragma unroll
      for (int ni = 0; ni < 4; ++ni) {
        acc[mi][ni] = mfma16(afl[mi], bfh[ni], acc[mi][ni]);
        acc[mi][ni] = mfma16(afh[mi], bfl[ni], acc[mi][ni]);
        acc[mi][ni] = mfma16(afh[mi], bfh[ni], acc[mi][ni]);
      }
    __syncthreads();
  }

  // ---- epilogue: gelu, halt partial dot, hi/lo plane writes via LDS repack
  float bv[4], hwv[4];
#pragma unroll
  for (int ni = 0; ni < 4; ++ni) {
    int col = bn0 + wc * 64 + ni * 16 + r16;
    bv[ni] = bias[col];
    hwv[ni] = halt_w[col];
  }
  float hv[4][4][4];  // [mi][ni][j]
  float zp[4][4];     // [mi][j]
#pragma unroll
  for (int mi = 0; mi < 4; ++mi)
#pragma unroll
    for (int j = 0; j < 4; ++j) {
      float zz = 0.0f;
#pragma unroll
      for (int ni = 0; ni < 4; ++ni) {
        float v = gelu_f(acc[mi][ni][j] + bv[ni]);
        hv[mi][ni][j] = v;
        zz += v * hwv[ni];
      }
      zp[mi][j] = zz;
    }
  // reduce across the 16-lane col groups (stays within each g-group)
#pragma unroll
  for (int off = 1; off < 16; off <<= 1)
#pragma unroll
    for (int mi = 0; mi < 4; ++mi)
#pragma unroll
      for (int j = 0; j < 4; ++j) zp[mi][j] += __shfl_xor(zp[mi][j], off);
  if (wc == 0 && r16 == 0) {
#pragma unroll
    for (int mi = 0; mi < 4; ++mi)
#pragma unroll
      for (int j = 0; j < 4; ++j) zs[wr * 64 + mi * 16 + g * 4 + j] = zp[mi][j];
  }
  __syncthreads();
  if (wc == 1 && r16 == 0) {
#pragma unroll
    for (int mi = 0; mi < 4; ++mi)
#pragma unroll
      for (int j = 0; j < 4; ++j) zs[wr * 64 + mi * 16 + g * 4 + j] += zp[mi][j];
  }
  __syncthreads();
  if (t < 128) zpart[(size_t)(bn0 >> 7) * M + bm0 + t] = zs[t];

  // repack hi plane through LDS for coalesced 16B stores
  u16* ht = (u16*)&stage[0][0][0][0];  // [128][128]
#pragma unroll
  for (int mi = 0; mi < 4; ++mi)
#pragma unroll
    for (int ni = 0; ni < 4; ++ni)
#pragma unroll
      for (int j = 0; j < 4; ++j)
        ht[(wr * 64 + mi * 16 + g * 4 + j) * 128 + wc * 64 + ni * 16 + r16] =
            f2bf(hv[mi][ni][j]);
  __syncthreads();
#pragma unroll
  for (int p = 0; p < 8; ++p) {
    int idx = p * 256 + t;
    int r = idx >> 4, u = idx & 15;
    *(short8*)(Hh + (size_t)(bm0 + r) * D_DIM + bn0 + u * 8) =
        *(const short8*)&ht[r * 128 + u * 8];
  }
  __syncthreads();
  // lo plane
#pragma unroll
  for (int mi = 0; mi < 4; ++mi)
#pragma unroll
    for (int ni = 0; ni < 4; ++ni)
#pragma unroll
      for (int j = 0; j < 4; ++j) {
        float v = hv[mi][ni][j];
        float hif = bf2f(f2bf(v));
        ht[(wr * 64 + mi * 16 + g * 4 + j) * 128 + wc * 64 + ni * 16 + r16] =
            f2bf(v - hif);
      }
  __syncthreads();
#pragma unroll
  for (int p = 0; p < 8; ++p) {
    int idx = p * 256 + t;
    int r = idx >> 4, u = idx & 15;
    *(short8*)(Hl + (size_t)(bm0 + r) * D_DIM + bn0 + u * 8) =
        *(const short8*)&ht[r * 128 + u * 8];
  }
}

// Per-token ACT weight/state update for one step (sequential across steps).
__global__ __launch_bounds__(256) void act_weights_kernel(
    const float* __restrict__ zpart, const float* __restrict__ halt_b,
    float* __restrict__ cum, float* __restrict__ rem, float* __restrict__ pond,
    float* __restrict__ wout, int step, int last, int M) {
  int tok = blockIdx.x * 256 + threadIdx.x;
  float z = halt_b[0];
#pragma unroll
  for (int nb = 0; nb < 8; ++nb) z += zpart[(size_t)nb * M + tok];
  float p = 1.0f / (1.0f + expf(-z));
  float c, r, q;
  if (step == 0) {
    c = 0.0f; r = 1.0f; q = 0.0f;
  } else {
    c = cum[tok]; r = rem[tok]; q = pond[tok];
  }
  float weight = last ? r : (((c + p) >= 0.99f) ? r : p);
  q += weight;
  c += weight;
  r = fmaxf(1.0f - c, 0.0f);
  cum[tok] = c;
  rem[tok] = r;
  pond[tok] = q;
  wout[tok] = weight;
}

// out (+)= sum_s w_s * h_s   (h from hi/lo bf16 planes)
__global__ __launch_bounds__(256) void act_out_kernel(
    const u16* __restrict__ hbase, size_t pstride, const float* __restrict__ w,
    int nsteps, int accum, float* __restrict__ out, int M) {
  size_t gid = (size_t)blockIdx.x * 256 + threadIdx.x;
  int tok = (int)(gid >> 7);
  int off = ((int)gid & 127) * 8;
  size_t base = (size_t)tok * D_DIM + off;
  float o[8];
  if (accum) {
    float4 a = *(const float4*)(out + base);
    float4 b = *(const float4*)(out + base + 4);
    o[0] = a.x; o[1] = a.y; o[2] = a.z; o[3] = a.w;
    o[4] = b.x; o[5] = b.y; o[6] = b.z; o[7] = b.w;
  } else {
#pragma unroll
    for (int j = 0; j < 8; ++j) o[j] = 0.0f;
  }
  const size_t MD = (size_t)M * D_DIM;
  for (int s = 0; s < nsteps; ++s) {
    float ws = w[(size_t)s * M + tok];
    const u16* hh = hbase + (size_t)s * pstride;
    short8 hi = *(const short8*)(hh + base);
    short8 lo = *(const short8*)(hh + MD + base);
#pragma unroll
    for (int j = 0; j < 8; ++j)
      o[j] += ws * (bf2f((u16)hi[j]) + bf2f((u16)lo[j]));
  }
  *(float4*)(out + base) = make_float4(o[0], o[1], o[2], o[3]);
  *(float4*)(out + base + 4) = make_float4(o[4], o[5], o[6], o[7]);
}

__global__ __launch_bounds__(256) void ponder_reduce_kernel(
    const float* __restrict__ pond, float* __restrict__ o, int n) {
  __shared__ float sh[256];
  float a = 0.0f;
  for (int i = threadIdx.x; i < n; i += 256) a += pond[i];
  sh[threadIdx.x] = a;
  __syncthreads();
  for (int s = 128; s; s >>= 1) {
    if ((int)threadIdx.x < s) sh[threadIdx.x] += sh[threadIdx.x + s];
    __syncthreads();
  }
  if (threadIdx.x == 0) o[0] = sh[0] / (float)n;
}

extern "C" void kernel_launch(void* const* d_in, const int* in_sizes, int n_in,
                              void* d_out, int out_size, void* d_ws,
                              size_t ws_size, hipStream_t stream) {
  const float* x = (const float*)d_in[0];
  const float* layer_w = (const float*)d_in[1];
  const float* layer_b = (const float*)d_in[2];
  const float* halt_w = (const float*)d_in[3];
  const float* halt_b = (const float*)d_in[4];
  float* out = (float*)d_out;

  const int D = D_DIM;
  const int M = in_sizes[0] / D;        // 16384
  const int L = in_sizes[1] / (D * D);  // 4
  const size_t MD = (size_t)M * D, DD = (size_t)D * D;

  char* ws = (char*)d_ws;
  size_t off = 0;
  auto alloc = [&](size_t bytes) {
    void* p = ws + off;
    off += (bytes + 255) & ~(size_t)255;
    return p;
  };
  u16* Wslot = (u16*)alloc(2 * DD * sizeof(u16));         // hi, lo (one layer)
  float* zpart = (float*)alloc(8 * (size_t)M * 4);
  float* wbuf = (float*)alloc((size_t)L * M * 4);
  float* cum = (float*)alloc((size_t)M * 4);
  float* rem = (float*)alloc((size_t)M * 4);
  float* pond = (float*)alloc((size_t)M * 4);

  const size_t planeElems = 2 * MD;           // hi plane + lo plane (u16)
  const size_t planeBytes = planeElems * 2;   // 67.1 MB per step
  const size_t fixed = off;
  const bool deferred = (fixed + (size_t)(L + 1) * planeBytes) <= ws_size;
  const int nbufs = deferred ? (L + 1) : 2;
  u16* planes = (u16*)alloc((size_t)nbufs * planeBytes);

  // split x -> plane buffer 0
  prep_x_kernel<<<(unsigned)(MD / 1024), 256, 0, stream>>>(x, planes,
                                                           planes + MD);
  for (int s = 0; s < L; ++s) {
    u16* pin = planes + (size_t)(deferred ? s : (s & 1)) * planeElems;
    u16* pout = planes + (size_t)(deferred ? (s + 1) : ((s + 1) & 1)) * planeElems;
    prep_w_kernel<<<dim3(D / 64, D / 64), 256, 0, stream>>>(
        layer_w + (size_t)s * DD, Wslot, Wslot + DD);
    gemm_act_kernel<<<dim3(D / 128, M / 128), 256, 0, stream>>>(
        pin, pin + MD, Wslot, Wslot + DD, layer_b + (size_t)s * D, halt_w,
        pout, pout + MD, zpart, M);
    act_weights_kernel<<<M / 256, 256, 0, stream>>>(
        zpart, halt_b, cum, rem, pond, wbuf + (size_t)s * M, s,
        (s == L - 1) ? 1 : 0, M);
    if (!deferred)
      act_out_kernel<<<(unsigned)(MD / 2048), 256, 0, stream>>>(
          pout, 0, wbuf + (size_t)s * M, 1, (s > 0) ? 1 : 0, out, M);
  }
  if (deferred)
    act_out_kernel<<<(unsigned)(MD / 2048), 256, 0, stream>>>(
        planes + planeElems, planeElems, wbuf, L, 0, out, M);
  ponder_reduce_kernel<<<1, 256, 0, stream>>>(pond, out + MD, M);
}

// Round 3
// 632.583 us; speedup vs baseline: 1.9905x; 1.9905x over previous
//
#include <hip/hip_runtime.h>

typedef __attribute__((ext_vector_type(8))) short short8;
typedef __attribute__((ext_vector_type(4))) float f32x4;
typedef __attribute__((ext_vector_type(4))) unsigned short u16x4;
typedef unsigned short u16;

#define D_DIM 1024

__device__ __forceinline__ u16 f2bf(float f) {
  unsigned u = __builtin_bit_cast(unsigned, f);
  u += 0x7fffu + ((u >> 16) & 1u);
  return (u16)(u >> 16);
}
__device__ __forceinline__ float bf2f(u16 b) {
  return __builtin_bit_cast(float, ((unsigned)b) << 16);
}
// tanh-approx gelu matching jax.nn.gelu(approximate=True)
__device__ __forceinline__ float gelu_f(float x) {
  float i = 0.7978845608028654f * (x + 0.044715f * x * x * x);
  float ex = __builtin_amdgcn_exp2f(i * 2.885390081777927f);  // e^{2i}
  float th = 1.0f - 2.0f * __builtin_amdgcn_rcpf(ex + 1.0f);
  return 0.5f * x * (1.0f + th);
}

__device__ __forceinline__ f32x4 mfma16(short8 a, short8 b, f32x4 c) {
  return __builtin_amdgcn_mfma_f32_16x16x32_bf16(a, b, c, 0, 0, 0);
}

__device__ __forceinline__ void glds16(const void* g, void* l) {
  __builtin_amdgcn_global_load_lds(
      (const __attribute__((address_space(1))) void*)g,
      (__attribute__((address_space(3))) void*)l, 16, 0, 0);
}

// Split fp32 W[K][N] (one layer) into bf16 hi/lo, transposed to [N][K].
__global__ __launch_bounds__(256) void prep_w_kernel(
    const float* __restrict__ W, u16* __restrict__ Wth, u16* __restrict__ Wtl) {
  __shared__ float tile[64][65];
  const int t = threadIdx.x;
  const int k0 = blockIdx.x * 64, n0 = blockIdx.y * 64;
#pragma unroll
  for (int j = 0; j < 16; ++j) {
    int idx = t + 256 * j;
    int r = idx >> 6, c = idx & 63;
    tile[r][c] = W[(size_t)(k0 + r) * D_DIM + (n0 + c)];
  }
  __syncthreads();
#pragma unroll
  for (int j = 0; j < 16; ++j) {
    int idx = t + 256 * j;
    int r = idx >> 6, c = idx & 63;
    float f = tile[c][r];
    u16 hb = f2bf(f);
    u16 lb = f2bf(f - bf2f(hb));
    size_t oidx = (size_t)(n0 + r) * D_DIM + (k0 + c);
    Wth[oidx] = hb;
    Wtl[oidx] = lb;
  }
}

// Split fp32 x into bf16 hi/lo planes.
__global__ __launch_bounds__(256) void prep_x_kernel(
    const float* __restrict__ x, u16* __restrict__ xh, u16* __restrict__ xl) {
  size_t i = ((size_t)blockIdx.x * 256 + threadIdx.x) * 4;
  const float4 v = *(const float4*)(x + i);
  const float fv[4] = {v.x, v.y, v.z, v.w};
  u16x4 h4, l4;
#pragma unroll
  for (int c = 0; c < 4; ++c) {
    u16 hb = f2bf(fv[c]);
    h4[c] = hb;
    l4[c] = f2bf(fv[c] - bf2f(hb));
  }
  *(u16x4*)(xh + i) = h4;
  *(u16x4*)(xl + i) = l4;
}

// H' = gelu(H*W + b); zpart[nb][tok] = partial halt dot over this block's cols.
// LDS row-major [plane][128][32] (m97 layout): glds dest linear -> global
// reads are 64B-contiguous runs of 16 rows per instruction (coalesced).
__global__ __launch_bounds__(256) void gemm_act_kernel(
    const u16* __restrict__ Ah, const u16* __restrict__ Al,
    const u16* __restrict__ Bh, const u16* __restrict__ Bl,
    const float* __restrict__ bias, const float* __restrict__ halt_w,
    u16* __restrict__ Hh, u16* __restrict__ Hl, float* __restrict__ zpart,
    int M) {
  __shared__ u16 stage[4][128][32];  // 32 KiB
  __shared__ float zs[128];
  const int t = threadIdx.x;
  const int nwg = gridDim.x * gridDim.y;
  const int bid = blockIdx.y * gridDim.x + blockIdx.x;
  const int wg = (bid & 7) * (nwg >> 3) + (bid >> 3);  // 1024 % 8 == 0
  const int bn0 = (wg & 7) * 128;
  const int bm0 = (wg >> 3) * 128;
  const int lane = t & 63, wid = t >> 6;
  const int wr = wid >> 1, wc = wid & 1;
  const int g = lane >> 4, r16 = lane & 15;

  // wave `wid` stages plane `wid`; lane 4r+c -> row j*16+r, u16 col c*8
  const u16* splane = (wid == 0) ? Ah : (wid == 1) ? Al : (wid == 2) ? Bh : Bl;
  const int srow0 = (wid < 2) ? bm0 : bn0;
  const u16* sbase =
      splane + (size_t)(srow0 + (lane >> 2)) * D_DIM + (lane & 3) * 8;

  f32x4 acc[4][4];
#pragma unroll
  for (int i = 0; i < 4; ++i)
#pragma unroll
    for (int j = 0; j < 4; ++j) acc[i][j] = (f32x4)0.0f;

  for (int k0 = 0; k0 < D_DIM; k0 += 32) {
#pragma unroll
    for (int j = 0; j < 8; ++j)
      glds16(sbase + (size_t)j * 16 * D_DIM + k0, &stage[wid][j * 16][0]);
    __syncthreads();
    short8 afh[4], afl[4], bfh[4], bfl[4];
#pragma unroll
    for (int i = 0; i < 4; ++i) {
      const int ar = wr * 64 + i * 16 + r16;
      afh[i] = *(const short8*)&stage[0][ar][g * 8];
      afl[i] = *(const short8*)&stage[1][ar][g * 8];
      const int bc = wc * 64 + i * 16 + r16;
      bfh[i] = *(const short8*)&stage[2][bc][g * 8];
      bfl[i] = *(const short8*)&stage[3][bc][g * 8];
    }
#pragma unroll
    for (int mi = 0; mi < 4; ++mi)
#pragma unroll
      for (int ni = 0; ni < 4; ++ni) {
        acc[mi][ni] = mfma16(afl[mi], bfh[ni], acc[mi][ni]);
        acc[mi][ni] = mfma16(afh[mi], bfl[ni], acc[mi][ni]);
        acc[mi][ni] = mfma16(afh[mi], bfh[ni], acc[mi][ni]);
      }
    __syncthreads();
  }

  // ---- epilogue: gelu, halt partial dot, hi/lo plane writes via LDS repack
  float bv[4], hwv[4];
#pragma unroll
  for (int ni = 0; ni < 4; ++ni) {
    int col = bn0 + wc * 64 + ni * 16 + r16;
    bv[ni] = bias[col];
    hwv[ni] = halt_w[col];
  }
  float hv[4][4][4];  // [mi][ni][j]
  float zp[4][4];     // [mi][j]
#pragma unroll
  for (int mi = 0; mi < 4; ++mi)
#pragma unroll
    for (int j = 0; j < 4; ++j) {
      float zz = 0.0f;
#pragma unroll
      for (int ni = 0; ni < 4; ++ni) {
        float v = gelu_f(acc[mi][ni][j] + bv[ni]);
        hv[mi][ni][j] = v;
        zz += v * hwv[ni];
      }
      zp[mi][j] = zz;
    }
#pragma unroll
  for (int off = 1; off < 16; off <<= 1)
#pragma unroll
    for (int mi = 0; mi < 4; ++mi)
#pragma unroll
      for (int j = 0; j < 4; ++j) zp[mi][j] += __shfl_xor(zp[mi][j], off);
  if (wc == 0 && r16 == 0) {
#pragma unroll
    for (int mi = 0; mi < 4; ++mi)
#pragma unroll
      for (int j = 0; j < 4; ++j) zs[wr * 64 + mi * 16 + g * 4 + j] = zp[mi][j];
  }
  __syncthreads();
  if (wc == 1 && r16 == 0) {
#pragma unroll
    for (int mi = 0; mi < 4; ++mi)
#pragma unroll
      for (int j = 0; j < 4; ++j) zs[wr * 64 + mi * 16 + g * 4 + j] += zp[mi][j];
  }
  __syncthreads();
  if (t < 128) zpart[(size_t)(bn0 >> 7) * M + bm0 + t] = zs[t];

  u16* ht = (u16*)&stage[0][0][0];  // [128][128] scratch
#pragma unroll
  for (int mi = 0; mi < 4; ++mi)
#pragma unroll
    for (int ni = 0; ni < 4; ++ni)
#pragma unroll
      for (int j = 0; j < 4; ++j)
        ht[(wr * 64 + mi * 16 + g * 4 + j) * 128 + wc * 64 + ni * 16 + r16] =
            f2bf(hv[mi][ni][j]);
  __syncthreads();
#pragma unroll
  for (int p = 0; p < 8; ++p) {
    int idx = p * 256 + t;
    int r = idx >> 4, u = idx & 15;
    *(short8*)(Hh + (size_t)(bm0 + r) * D_DIM + bn0 + u * 8) =
        *(const short8*)&ht[r * 128 + u * 8];
  }
  __syncthreads();
#pragma unroll
  for (int mi = 0; mi < 4; ++mi)
#pragma unroll
    for (int ni = 0; ni < 4; ++ni)
#pragma unroll
      for (int j = 0; j < 4; ++j) {
        float v = hv[mi][ni][j];
        float hif = bf2f(f2bf(v));
        ht[(wr * 64 + mi * 16 + g * 4 + j) * 128 + wc * 64 + ni * 16 + r16] =
            f2bf(v - hif);
      }
  __syncthreads();
#pragma unroll
  for (int p = 0; p < 8; ++p) {
    int idx = p * 256 + t;
    int r = idx >> 4, u = idx & 15;
    *(short8*)(Hl + (size_t)(bm0 + r) * D_DIM + bn0 + u * 8) =
        *(const short8*)&ht[r * 128 + u * 8];
  }
}

// Per-token ACT weight/state update for one step (sequential across steps).
__global__ __launch_bounds__(256) void act_weights_kernel(
    const float* __restrict__ zpart, const float* __restrict__ halt_b,
    float* __restrict__ cum, float* __restrict__ rem, float* __restrict__ pond,
    float* __restrict__ wout, int step, int last, int M) {
  int tok = blockIdx.x * 256 + threadIdx.x;
  float z = halt_b[0];
#pragma unroll
  for (int nb = 0; nb < 8; ++nb) z += zpart[(size_t)nb * M + tok];
  float p = 1.0f / (1.0f + expf(-z));
  float c, r, q;
  if (step == 0) {
    c = 0.0f; r = 1.0f; q = 0.0f;
  } else {
    c = cum[tok]; r = rem[tok]; q = pond[tok];
  }
  float weight = last ? r : (((c + p) >= 0.99f) ? r : p);
  q += weight;
  c += weight;
  r = fmaxf(1.0f - c, 0.0f);
  cum[tok] = c;
  rem[tok] = r;
  pond[tok] = q;
  wout[tok] = weight;
}

// out (+)= sum_s w_s * h_s   (h from hi/lo bf16 planes)
__global__ __launch_bounds__(256) void act_out_kernel(
    const u16* __restrict__ hbase, size_t pstride, const float* __restrict__ w,
    int nsteps, int accum, float* __restrict__ out, int M) {
  size_t gid = (size_t)blockIdx.x * 256 + threadIdx.x;
  int tok = (int)(gid >> 7);
  int off = ((int)gid & 127) * 8;
  size_t base = (size_t)tok * D_DIM + off;
  float o[8];
  if (accum) {
    float4 a = *(const float4*)(out + base);
    float4 b = *(const float4*)(out + base + 4);
    o[0] = a.x; o[1] = a.y; o[2] = a.z; o[3] = a.w;
    o[4] = b.x; o[5] = b.y; o[6] = b.z; o[7] = b.w;
  } else {
#pragma unroll
    for (int j = 0; j < 8; ++j) o[j] = 0.0f;
  }
  const size_t MD = (size_t)M * D_DIM;
  for (int s = 0; s < nsteps; ++s) {
    float ws = w[(size_t)s * M + tok];
    const u16* hh = hbase + (size_t)s * pstride;
    short8 hi = *(const short8*)(hh + base);
    short8 lo = *(const short8*)(hh + MD + base);
#pragma unroll
    for (int j = 0; j < 8; ++j)
      o[j] += ws * (bf2f((u16)hi[j]) + bf2f((u16)lo[j]));
  }
  *(float4*)(out + base) = make_float4(o[0], o[1], o[2], o[3]);
  *(float4*)(out + base + 4) = make_float4(o[4], o[5], o[6], o[7]);
}

__global__ __launch_bounds__(256) void ponder_reduce_kernel(
    const float* __restrict__ pond, float* __restrict__ o, int n) {
  __shared__ float sh[256];
  float a = 0.0f;
  for (int i = threadIdx.x; i < n; i += 256) a += pond[i];
  sh[threadIdx.x] = a;
  __syncthreads();
  for (int s = 128; s; s >>= 1) {
    if ((int)threadIdx.x < s) sh[threadIdx.x] += sh[threadIdx.x + s];
    __syncthreads();
  }
  if (threadIdx.x == 0) o[0] = sh[0] / (float)n;
}

extern "C" void kernel_launch(void* const* d_in, const int* in_sizes, int n_in,
                              void* d_out, int out_size, void* d_ws,
                              size_t ws_size, hipStream_t stream) {
  const float* x = (const float*)d_in[0];
  const float* layer_w = (const float*)d_in[1];
  const float* layer_b = (const float*)d_in[2];
  const float* halt_w = (const float*)d_in[3];
  const float* halt_b = (const float*)d_in[4];
  float* out = (float*)d_out;

  const int D = D_DIM;
  const int M = in_sizes[0] / D;        // 16384
  const int L = in_sizes[1] / (D * D);  // 4
  const size_t MD = (size_t)M * D, DD = (size_t)D * D;

  char* ws = (char*)d_ws;
  size_t off = 0;
  auto alloc = [&](size_t bytes) {
    void* p = ws + off;
    off += (bytes + 255) & ~(size_t)255;
    return p;
  };
  u16* Wslot = (u16*)alloc(2 * DD * sizeof(u16));  // hi, lo (one layer)
  float* zpart = (float*)alloc(8 * (size_t)M * 4);
  float* wbuf = (float*)alloc((size_t)L * M * 4);
  float* cum = (float*)alloc((size_t)M * 4);
  float* rem = (float*)alloc((size_t)M * 4);
  float* pond = (float*)alloc((size_t)M * 4);

  const size_t planeElems = 2 * MD;          // hi plane + lo plane (u16)
  const size_t planeBytes = planeElems * 2;  // 67.1 MB per step
  const size_t fixed = off;
  const bool deferred = (fixed + (size_t)(L + 1) * planeBytes) <= ws_size;
  const int nbufs = deferred ? (L + 1) : 2;
  u16* planes = (u16*)alloc((size_t)nbufs * planeBytes);

  prep_x_kernel<<<(unsigned)(MD / 1024), 256, 0, stream>>>(x, planes,
                                                           planes + MD);
  for (int s = 0; s < L; ++s) {
    u16* pin = planes + (size_t)(deferred ? s : (s & 1)) * planeElems;
    u16* pout =
        planes + (size_t)(deferred ? (s + 1) : ((s + 1) & 1)) * planeElems;
    prep_w_kernel<<<dim3(D / 64, D / 64), 256, 0, stream>>>(
        layer_w + (size_t)s * DD, Wslot, Wslot + DD);
    gemm_act_kernel<<<dim3(D / 128, M / 128), 256, 0, stream>>>(
        pin, pin + MD, Wslot, Wslot + DD, layer_b + (size_t)s * D, halt_w,
        pout, pout + MD, zpart, M);
    act_weights_kernel<<<M / 256, 256, 0, stream>>>(
        zpart, halt_b, cum, rem, pond, wbuf + (size_t)s * M, s,
        (s == L - 1) ? 1 : 0, M);
    if (!deferred)
      act_out_kernel<<<(unsigned)(MD / 2048), 256, 0, stream>>>(
          pout, 0, wbuf + (size_t)s * M, 1, (s > 0) ? 1 : 0, out, M);
  }
  if (deferred)
    act_out_kernel<<<(unsigned)(MD / 2048), 256, 0, stream>>>(
        planes + planeElems, planeElems, wbuf, L, 0, out, M);
  ponder_reduce_kernel<<<1, 256, 0, stream>>>(pond, out + MD, M);
}

// Round 4
// 615.140 us; speedup vs baseline: 2.0469x; 1.0284x over previous
//
#include <hip/hip_runtime.h>

typedef __attribute__((ext_vector_type(8))) short short8;
typedef __attribute__((ext_vector_type(4))) float f32x4;
typedef __attribute__((ext_vector_type(4))) unsigned short u16x4;
typedef unsigned short u16;

#define D_DIM 1024
#define NT 48  // 3 plane-passes x 16 K-tiles of BK=64

__device__ __forceinline__ u16 f2bf(float f) {
  unsigned u = __builtin_bit_cast(unsigned, f);
  u += 0x7fffu + ((u >> 16) & 1u);
  return (u16)(u >> 16);
}
__device__ __forceinline__ float bf2f(u16 b) {
  return __builtin_bit_cast(float, ((unsigned)b) << 16);
}
__device__ __forceinline__ float gelu_f(float x) {
  float i = 0.7978845608028654f * (x + 0.044715f * x * x * x);
  float ex = __builtin_amdgcn_exp2f(i * 2.885390081777927f);  // e^{2i}
  float th = 1.0f - 2.0f * __builtin_amdgcn_rcpf(ex + 1.0f);
  return 0.5f * x * (1.0f + th);
}
__device__ __forceinline__ f32x4 mfma16(short8 a, short8 b, f32x4 c) {
  return __builtin_amdgcn_mfma_f32_16x16x32_bf16(a, b, c, 0, 0, 0);
}
__device__ __forceinline__ void glds16(const void* g, void* l) {
  __builtin_amdgcn_global_load_lds(
      (const __attribute__((address_space(1))) void*)g,
      (__attribute__((address_space(3))) void*)l, 16, 0, 0);
}

// ---------------- prep kernels ----------------
__global__ __launch_bounds__(256) void prep_w_kernel(
    const float* __restrict__ W, u16* __restrict__ Wth, u16* __restrict__ Wtl) {
  __shared__ float tile[64][65];
  const int t = threadIdx.x;
  const int k0 = blockIdx.x * 64, n0 = blockIdx.y * 64;
  const size_t lbase = (size_t)blockIdx.z * D_DIM * D_DIM;
#pragma unroll
  for (int j = 0; j < 16; ++j) {
    int idx = t + 256 * j;
    int r = idx >> 6, c = idx & 63;
    tile[r][c] = W[lbase + (size_t)(k0 + r) * D_DIM + (n0 + c)];
  }
  __syncthreads();
#pragma unroll
  for (int j = 0; j < 16; ++j) {
    int idx = t + 256 * j;
    int r = idx >> 6, c = idx & 63;
    float f = tile[c][r];
    u16 hb = f2bf(f);
    u16 lb = f2bf(f - bf2f(hb));
    size_t oidx = lbase + (size_t)(n0 + r) * D_DIM + (k0 + c);
    Wth[oidx] = hb;
    Wtl[oidx] = lb;
  }
}

__global__ __launch_bounds__(256) void prep_x_kernel(
    const float* __restrict__ x, u16* __restrict__ xh, u16* __restrict__ xl) {
  size_t i = ((size_t)blockIdx.x * 256 + threadIdx.x) * 4;
  const float4 v = *(const float4*)(x + i);
  const float fv[4] = {v.x, v.y, v.z, v.w};
  u16x4 h4, l4;
#pragma unroll
  for (int c = 0; c < 4; ++c) {
    u16 hb = f2bf(fv[c]);
    h4[c] = hb;
    l4[c] = f2bf(fv[c] - bf2f(hb));
  }
  *(u16x4*)(xh + i) = h4;
  *(u16x4*)(xl + i) = l4;
}

// ---------------- 256x256 8-phase GEMM + ACT epilogue ----------------
template <int BUF, int C, int MH>
__device__ __forceinline__ void phase_mma(const u16* lds, const int* a_rd,
                                          const int* b_rd, f32x4 (&acc)[8][4],
                                          short8 (&bfr)[4]) {
  const u16* Lb = lds + BUF * 32768;
  short8 af[4];
#pragma unroll
  for (int i = 0; i < 4; ++i)
    af[i] = *(const short8*)(Lb + a_rd[C] + (MH * 4 + i) * 1024);
  if (MH == 0) {
#pragma unroll
    for (int n = 0; n < 4; ++n)
      bfr[n] = *(const short8*)(Lb + b_rd[C] + n * 1024);
  }
  __builtin_amdgcn_s_setprio(1);
#pragma unroll
  for (int i = 0; i < 4; ++i)
#pragma unroll
    for (int n = 0; n < 4; ++n)
      acc[MH * 4 + i][n] = mfma16(af[i], bfr[n], acc[MH * 4 + i][n]);
  __builtin_amdgcn_s_setprio(0);
}

__global__ __launch_bounds__(512, 2) void gemm_act_kernel(
    const u16* __restrict__ Ah, const u16* __restrict__ Al,
    const u16* __restrict__ Bh, const u16* __restrict__ Bl,
    const float* __restrict__ bias, const float* __restrict__ halt_w,
    u16* __restrict__ Hh, u16* __restrict__ Hl, float* __restrict__ zpart,
    int M) {
  extern __shared__ u16 lds[];  // 2 bufs x (A 32KB + B 32KB) = 128 KiB
  const int t = threadIdx.x;
  const int bid = blockIdx.x;  // 256 blocks
  const int wg = (bid & 7) * 32 + (bid >> 3);  // XCD-chunked, bijective (256%8==0)
  const int bn0 = (wg & 3) * 256;
  const int bm0 = (wg >> 2) * 256;
  const int lane = t & 63, wid = t >> 6;
  const int wr = wid >> 2, wc = wid & 3;
  const int g = lane >> 4, r16 = lane & 15;

  // staging: per-thread source offset (u16) within a 128-row pair-block.
  // LDS slot s of row r holds global chunk s ^ (r&7)  (bank-uniform swizzle).
  const int trow = t >> 3;                       // 0..63
  const int tchunk = (t & 7) ^ (trow & 7);
  const int src_off = trow * 1024 + tchunk * 8;  // u16 units

  // fragment read offsets (u16), per k-half C
  int a_rd[2], b_rd[2];
#pragma unroll
  for (int c = 0; c < 2; ++c) {
    int swz = ((c * 4 + g) ^ (r16 & 7)) * 8;
    a_rd[c] = wr * 8192 + r16 * 64 + swz;
    b_rd[c] = 16384 + wc * 4096 + r16 * 64 + swz;
  }

  const size_t abase = (size_t)bm0 * 1024;
  const size_t bbase = (size_t)bn0 * 1024;

  auto stage = [&](int kt, int p) {  // p=0,1: A row-pairs; p=2,3: B row-pairs
    if (kt >= NT) return;
    const int pass = kt >> 4;
    const int k0 = (kt & 15) << 6;
    const int buf = kt & 1;
    if (p < 2) {
      const u16* s = ((pass == 1) ? Al : Ah) + abase + k0 + src_off +
                     (size_t)p * 131072;
      char* d = (char*)lds + buf * 65536 + p * 16384 + wid * 1024;
      glds16(s, d);
      glds16(s + 65536, d + 8192);
    } else {
      const u16* s = ((pass == 2) ? Bl : Bh) + bbase + k0 + src_off +
                     (size_t)(p - 2) * 131072;
      char* d = (char*)lds + buf * 65536 + 32768 + (p - 2) * 16384 + wid * 1024;
      glds16(s, d);
      glds16(s + 65536, d + 8192);
    }
  };

  f32x4 acc[8][4];
#pragma unroll
  for (int i = 0; i < 8; ++i)
#pragma unroll
    for (int j = 0; j < 4; ++j) acc[i][j] = (f32x4)0.0f;
  short8 bfr[4];

#define SEAL() asm volatile("s_waitcnt vmcnt(0)" ::: "memory")
#define BAR()                          \
  asm volatile("" ::: "memory");       \
  __builtin_amdgcn_s_barrier();        \
  asm volatile("" ::: "memory")

  // prologue: fully stage tile 0 into buf0
  stage(0, 0); stage(0, 1); stage(0, 2); stage(0, 3);

#pragma unroll 1
  for (int i = 0; i < NT / 2; ++i) {
    const int T1 = 2 * i + 1, T2 = 2 * i + 2;
    // phases 0-3: compute tile 2i (buf0), stage T1 -> buf1
    SEAL(); BAR(); stage(T1, 0); phase_mma<0, 0, 0>(lds, a_rd, b_rd, acc, bfr);
    BAR();         stage(T1, 1); phase_mma<0, 0, 1>(lds, a_rd, b_rd, acc, bfr);
    BAR();         stage(T1, 2); phase_mma<0, 1, 0>(lds, a_rd, b_rd, acc, bfr);
    BAR();         stage(T1, 3); phase_mma<0, 1, 1>(lds, a_rd, b_rd, acc, bfr);
    // phases 4-7: compute tile 2i+1 (buf1), stage T2 -> buf0
    SEAL(); BAR(); stage(T2, 0); phase_mma<1, 0, 0>(lds, a_rd, b_rd, acc, bfr);
    BAR();         stage(T2, 1); phase_mma<1, 0, 1>(lds, a_rd, b_rd, acc, bfr);
    BAR();         stage(T2, 2); phase_mma<1, 1, 0>(lds, a_rd, b_rd, acc, bfr);
    BAR();         stage(T2, 3); phase_mma<1, 1, 1>(lds, a_rd, b_rd, acc, bfr);
  }
#undef SEAL
#undef BAR

  __syncthreads();  // all reads done; no glds outstanding (tile 48 skipped)

  // ---- epilogue: bias + gelu (in place), halt partial dot
  float bv[4], hwv[4];
#pragma unroll
  for (int ni = 0; ni < 4; ++ni) {
    int col = bn0 + wc * 64 + ni * 16 + r16;
    bv[ni] = bias[col];
    hwv[ni] = halt_w[col];
  }
  float zp[8][4];
#pragma unroll
  for (int mi = 0; mi < 8; ++mi)
#pragma unroll
    for (int j = 0; j < 4; ++j) {
      float zz = 0.0f;
#pragma unroll
      for (int ni = 0; ni < 4; ++ni) {
        float v = gelu_f(acc[mi][ni][j] + bv[ni]);
        acc[mi][ni][j] = v;
        zz += v * hwv[ni];
      }
      zp[mi][j] = zz;
    }
#pragma unroll
  for (int off = 1; off < 16; off <<= 1)
#pragma unroll
    for (int mi = 0; mi < 8; ++mi)
#pragma unroll
      for (int j = 0; j < 4; ++j) zp[mi][j] += __shfl_xor(zp[mi][j], off);
  float* zf = (float*)lds;  // [4][256]
  if (r16 == 0) {
#pragma unroll
    for (int mi = 0; mi < 8; ++mi)
#pragma unroll
      for (int j = 0; j < 4; ++j)
        zf[wc * 256 + wr * 128 + mi * 16 + g * 4 + j] = zp[mi][j];
  }
  __syncthreads();
  if (t < 256) {
    float z = zf[t] + zf[256 + t] + zf[512 + t] + zf[768 + t];
    zpart[(size_t)(bn0 >> 8) * M + bm0 + t] = z;
  }
  __syncthreads();

  // ---- hi plane repack + store
  u16* hp = lds;  // [256][256]
#pragma unroll
  for (int mi = 0; mi < 8; ++mi)
#pragma unroll
    for (int ni = 0; ni < 4; ++ni)
#pragma unroll
      for (int j = 0; j < 4; ++j)
        hp[(wr * 128 + mi * 16 + g * 4 + j) * 256 + wc * 64 + ni * 16 + r16] =
            f2bf(acc[mi][ni][j]);
  __syncthreads();
#pragma unroll
  for (int q = 0; q < 16; ++q) {
    int idx = q * 512 + t;
    int r = idx >> 5, cc = idx & 31;
    *(short8*)(Hh + (size_t)(bm0 + r) * D_DIM + bn0 + cc * 8) =
        *(const short8*)&hp[r * 256 + cc * 8];
  }
  __syncthreads();
  // ---- lo plane
#pragma unroll
  for (int mi = 0; mi < 8; ++mi)
#pragma unroll
    for (int ni = 0; ni < 4; ++ni)
#pragma unroll
      for (int j = 0; j < 4; ++j) {
        float v = acc[mi][ni][j];
        hp[(wr * 128 + mi * 16 + g * 4 + j) * 256 + wc * 64 + ni * 16 + r16] =
            f2bf(v - bf2f(f2bf(v)));
      }
  __syncthreads();
#pragma unroll
  for (int q = 0; q < 16; ++q) {
    int idx = q * 512 + t;
    int r = idx >> 5, cc = idx & 31;
    *(short8*)(Hl + (size_t)(bm0 + r) * D_DIM + bn0 + cc * 8) =
        *(const short8*)&hp[r * 256 + cc * 8];
  }
}

// ---------------- ACT scalar kernels ----------------
__global__ __launch_bounds__(256) void act_weights_kernel(
    const float* __restrict__ zpart, const float* __restrict__ halt_b,
    float* __restrict__ cum, float* __restrict__ rem, float* __restrict__ pond,
    float* __restrict__ wout, int step, int last, int M, int nblk) {
  int tok = blockIdx.x * 256 + threadIdx.x;
  float z = halt_b[0];
  for (int nb = 0; nb < nblk; ++nb) z += zpart[(size_t)nb * M + tok];
  float p = 1.0f / (1.0f + expf(-z));
  float c, r, q;
  if (step == 0) {
    c = 0.0f; r = 1.0f; q = 0.0f;
  } else {
    c = cum[tok]; r = rem[tok]; q = pond[tok];
  }
  float weight = last ? r : (((c + p) >= 0.99f) ? r : p);
  q += weight;
  c += weight;
  r = fmaxf(1.0f - c, 0.0f);
  cum[tok] = c;
  rem[tok] = r;
  pond[tok] = q;
  wout[tok] = weight;
}

__global__ __launch_bounds__(256) void act_out_kernel(
    const u16* __restrict__ hbase, size_t pstride, const float* __restrict__ w,
    int nsteps, int accum, float* __restrict__ out, int M) {
  size_t gid = (size_t)blockIdx.x * 256 + threadIdx.x;
  int tok = (int)(gid >> 7);
  int off = ((int)gid & 127) * 8;
  size_t base = (size_t)tok * D_DIM + off;
  float o[8];
  if (accum) {
    float4 a = *(const float4*)(out + base);
    float4 b = *(const float4*)(out + base + 4);
    o[0] = a.x; o[1] = a.y; o[2] = a.z; o[3] = a.w;
    o[4] = b.x; o[5] = b.y; o[6] = b.z; o[7] = b.w;
  } else {
#pragma unroll
    for (int j = 0; j < 8; ++j) o[j] = 0.0f;
  }
  const size_t MD = (size_t)M * D_DIM;
  for (int s = 0; s < nsteps; ++s) {
    float ws = w[(size_t)s * M + tok];
    const u16* hh = hbase + (size_t)s * pstride;
    short8 hi = *(const short8*)(hh + base);
    short8 lo = *(const short8*)(hh + MD + base);
#pragma unroll
    for (int j = 0; j < 8; ++j)
      o[j] += ws * (bf2f((u16)hi[j]) + bf2f((u16)lo[j]));
  }
  *(float4*)(out + base) = make_float4(o[0], o[1], o[2], o[3]);
  *(float4*)(out + base + 4) = make_float4(o[4], o[5], o[6], o[7]);
}

__global__ __launch_bounds__(256) void ponder_reduce_kernel(
    const float* __restrict__ pond, float* __restrict__ o, int n) {
  __shared__ float sh[256];
  float a = 0.0f;
  for (int i = threadIdx.x; i < n; i += 256) a += pond[i];
  sh[threadIdx.x] = a;
  __syncthreads();
  for (int s = 128; s; s >>= 1) {
    if ((int)threadIdx.x < s) sh[threadIdx.x] += sh[threadIdx.x + s];
    __syncthreads();
  }
  if (threadIdx.x == 0) o[0] = sh[0] / (float)n;
}

extern "C" void kernel_launch(void* const* d_in, const int* in_sizes, int n_in,
                              void* d_out, int out_size, void* d_ws,
                              size_t ws_size, hipStream_t stream) {
  const float* x = (const float*)d_in[0];
  const float* layer_w = (const float*)d_in[1];
  const float* layer_b = (const float*)d_in[2];
  const float* halt_w = (const float*)d_in[3];
  const float* halt_b = (const float*)d_in[4];
  float* out = (float*)d_out;

  const int D = D_DIM;
  const int M = in_sizes[0] / D;        // 16384
  const int L = in_sizes[1] / (D * D);  // 4
  const size_t MD = (size_t)M * D, DD = (size_t)D * D;

  char* ws = (char*)d_ws;
  size_t off = 0;
  auto alloc = [&](size_t bytes) {
    void* p = ws + off;
    off += (bytes + 255) & ~(size_t)255;
    return p;
  };
  u16* Wsplit = (u16*)alloc((size_t)L * 2 * DD * sizeof(u16));  // per-layer hi|lo
  float* zpart = (float*)alloc(4 * (size_t)M * 4);
  float* wbuf = (float*)alloc((size_t)L * M * 4);
  float* cum = (float*)alloc((size_t)M * 4);
  float* rem = (float*)alloc((size_t)M * 4);
  float* pond = (float*)alloc((size_t)M * 4);

  const size_t planeElems = 2 * MD;          // hi + lo (u16)
  const size_t planeBytes = planeElems * 2;  // 67.1 MB
  const bool deferred = (off + (size_t)(L + 1) * planeBytes) <= ws_size;
  const int nbufs = deferred ? (L + 1) : 2;
  u16* planes = (u16*)alloc((size_t)nbufs * planeBytes);

  hipFuncSetAttribute((const void*)gemm_act_kernel,
                      hipFuncAttributeMaxDynamicSharedMemorySize, 131072);

  prep_x_kernel<<<(unsigned)(MD / 1024), 256, 0, stream>>>(x, planes,
                                                           planes + MD);
  prep_w_kernel<<<dim3(D / 64, D / 64, L), 256, 0, stream>>>(
      layer_w, Wsplit, Wsplit + (size_t)L * DD);

  for (int s = 0; s < L; ++s) {
    u16* pin = planes + (size_t)(deferred ? s : (s & 1)) * planeElems;
    u16* pout =
        planes + (size_t)(deferred ? (s + 1) : ((s + 1) & 1)) * planeElems;
    gemm_act_kernel<<<dim3(M / 256 * (D / 256)), 512, 131072, stream>>>(
        pin, pin + MD, Wsplit + (size_t)s * DD,
        Wsplit + (size_t)(L + s) * DD, layer_b + (size_t)s * D, halt_w, pout,
        pout + MD, zpart, M);
    act_weights_kernel<<<M / 256, 256, 0, stream>>>(
        zpart, halt_b, cum, rem, pond, wbuf + (size_t)s * M, s,
        (s == L - 1) ? 1 : 0, M, D / 256);
    if (!deferred)
      act_out_kernel<<<(unsigned)(MD / 2048), 256, 0, stream>>>(
          pout, 0, wbuf + (size_t)s * M, 1, (s > 0) ? 1 : 0, out, M);
  }
  if (deferred)
    act_out_kernel<<<(unsigned)(MD / 2048), 256, 0, stream>>>(
        planes + planeElems, planeElems, wbuf, L, 0, out, M);
  ponder_reduce_kernel<<<1, 256, 0, stream>>>(pond, out + MD, M);
}

// Round 5
// 598.150 us; speedup vs baseline: 2.1051x; 1.0284x over previous
//
#include <hip/hip_runtime.h>

typedef __attribute__((ext_vector_type(8))) short short8;
typedef __attribute__((ext_vector_type(4))) float f32x4;
typedef __attribute__((ext_vector_type(4))) unsigned short u16x4;
typedef unsigned short u16;

#define D_DIM 1024
#define NKT 32  // K / 32, fused hi/lo per slice

__device__ __forceinline__ u16 f2bf(float f) {
  unsigned u = __builtin_bit_cast(unsigned, f);
  u += 0x7fffu + ((u >> 16) & 1u);
  return (u16)(u >> 16);
}
__device__ __forceinline__ float bf2f(u16 b) {
  return __builtin_bit_cast(float, ((unsigned)b) << 16);
}
__device__ __forceinline__ float gelu_f(float x) {
  float i = 0.7978845608028654f * (x + 0.044715f * x * x * x);
  float ex = __builtin_amdgcn_exp2f(i * 2.885390081777927f);  // e^{2i}
  float th = 1.0f - 2.0f * __builtin_amdgcn_rcpf(ex + 1.0f);
  return 0.5f * x * (1.0f + th);
}
__device__ __forceinline__ f32x4 mfma16(short8 a, short8 b, f32x4 c) {
  return __builtin_amdgcn_mfma_f32_16x16x32_bf16(a, b, c, 0, 0, 0);
}
__device__ __forceinline__ void glds16(const u16* g, const u16* l) {
  __builtin_amdgcn_global_load_lds(
      (const __attribute__((address_space(1))) void*)g,
      (__attribute__((address_space(3))) void*)l, 16, 0, 0);
}

// ---------------- prep kernels ----------------
__global__ __launch_bounds__(256) void prep_w_kernel(
    const float* __restrict__ W, u16* __restrict__ Wth, u16* __restrict__ Wtl) {
  __shared__ float tile[64][65];
  const int t = threadIdx.x;
  const int k0 = blockIdx.x * 64, n0 = blockIdx.y * 64;
  const size_t lbase = (size_t)blockIdx.z * D_DIM * D_DIM;
#pragma unroll
  for (int j = 0; j < 16; ++j) {
    int idx = t + 256 * j;
    int r = idx >> 6, c = idx & 63;
    tile[r][c] = W[lbase + (size_t)(k0 + r) * D_DIM + (n0 + c)];
  }
  __syncthreads();
#pragma unroll
  for (int j = 0; j < 16; ++j) {
    int idx = t + 256 * j;
    int r = idx >> 6, c = idx & 63;
    float f = tile[c][r];
    u16 hb = f2bf(f);
    u16 lb = f2bf(f - bf2f(hb));
    size_t oidx = lbase + (size_t)(n0 + r) * D_DIM + (k0 + c);
    Wth[oidx] = hb;
    Wtl[oidx] = lb;
  }
}

__global__ __launch_bounds__(256) void prep_x_kernel(
    const float* __restrict__ x, u16* __restrict__ xh, u16* __restrict__ xl) {
  size_t i = ((size_t)blockIdx.x * 256 + threadIdx.x) * 4;
  const float4 v = *(const float4*)(x + i);
  const float fv[4] = {v.x, v.y, v.z, v.w};
  u16x4 h4, l4;
#pragma unroll
  for (int c = 0; c < 4; ++c) {
    u16 hb = f2bf(fv[c]);
    h4[c] = hb;
    l4[c] = f2bf(fv[c] - bf2f(hb));
  }
  *(u16x4*)(xh + i) = h4;
  *(u16x4*)(xl + i) = l4;
}

// ---------------- 256x256 fused-plane GEMM + ACT epilogue ----------------
// LDS buffer (per kt parity): Ah[256][32] | Al | Bh | Bl, each 8192 u16.
// Slot s of row r holds k-chunk s ^ ((r^(r>>2))&3)  (bank-spread involution).
__global__ __launch_bounds__(512, 2) void gemm_act_kernel(
    const u16* __restrict__ Ahp, const u16* __restrict__ Alp,
    const u16* __restrict__ Bhp, const u16* __restrict__ Blp,
    const float* __restrict__ bias, const float* __restrict__ halt_w,
    u16* __restrict__ Hh, u16* __restrict__ Hl, float* __restrict__ zpart,
    int M) {
  extern __shared__ u16 lds[];  // 2 x 64 KiB
  const int t = threadIdx.x;
  const int bid = blockIdx.x;                  // 256 blocks
  const int wg = (bid & 7) * 32 + (bid >> 3);  // XCD-chunked, bijective
  const int bn0 = (wg & 3) * 256;
  const int bm0 = (wg >> 2) * 256;
  const int lane = t & 63, wid = t >> 6;
  const int wr = wid >> 2, wc = wid & 3;
  const int g = lane >> 4, r16 = lane & 15;

  // staging source offset: row-in-part rip, slot lane&3 -> chunk via XOR
  const int rip = (wid << 4) + (lane >> 2);  // 0..127
  const int chunk = (lane & 3) ^ ((rip ^ (rip >> 2)) & 3);
  const int soff = rip * 1024 + chunk * 8;  // u16

  // fragment read offset (u16), within a plane
  const int fslot = (g ^ (r16 ^ (r16 >> 2))) & 3;
  const int rdoff = r16 * 32 + fslot * 8;

  const size_t abase = (size_t)bm0 * 1024;
  const size_t bbase = (size_t)bn0 * 1024;
  const u16* aS = Ahp + abase + soff;
  const u16* lS = Alp + abase + soff;
  const u16* bS = Bhp + bbase + soff;
  const u16* cS = Blp + bbase + soff;
  u16* dst0 = lds + wid * 512;

  auto stage = [&](int kt) {
    const int k0 = kt << 5;
    u16* Lb = dst0 + (kt & 1) * 32768;
    glds16(aS + k0, Lb);
    glds16(aS + k0 + 131072, Lb + 4096);
    glds16(lS + k0, Lb + 8192);
    glds16(lS + k0 + 131072, Lb + 12288);
    glds16(bS + k0, Lb + 16384);
    glds16(bS + k0 + 131072, Lb + 20480);
    glds16(cS + k0, Lb + 24576);
    glds16(cS + k0 + 131072, Lb + 28672);
  };

  f32x4 acc[8][4];
#pragma unroll
  for (int i = 0; i < 8; ++i)
#pragma unroll
    for (int j = 0; j < 4; ++j) acc[i][j] = (f32x4)0.0f;

#define BAR()                    \
  asm volatile("" ::: "memory"); \
  __builtin_amdgcn_s_barrier();  \
  asm volatile("" ::: "memory")

  stage(0);
#pragma unroll 1
  for (int kt = 0; kt < NKT; ++kt) {
    BAR();  // all waves done reading buf[(kt+1)&1] (tile kt-1)
    if (kt + 1 < NKT) {
      stage(kt + 1);
      asm volatile("s_waitcnt vmcnt(8)" ::: "memory");  // tile kt landed
    } else {
      asm volatile("s_waitcnt vmcnt(0)" ::: "memory");
    }
    BAR();  // everyone's tile kt landed
    const u16* Lb = lds + (kt & 1) * 32768;
    short8 bh[4], bl[4];
#pragma unroll
    for (int mh = 0; mh < 2; ++mh) {
      short8 ah[4], al[4];
      const int ab = wr * 4096 + mh * 2048 + rdoff;
#pragma unroll
      for (int i = 0; i < 4; ++i) ah[i] = *(const short8*)(Lb + ab + i * 512);
      if (mh == 0) {
#pragma unroll
        for (int n = 0; n < 4; ++n)
          bh[n] = *(const short8*)(Lb + 16384 + wc * 2048 + n * 512 + rdoff);
      }
      __builtin_amdgcn_s_setprio(1);
#pragma unroll
      for (int i = 0; i < 4; ++i)
#pragma unroll
        for (int n = 0; n < 4; ++n)
          acc[mh * 4 + i][n] = mfma16(ah[i], bh[n], acc[mh * 4 + i][n]);
      __builtin_amdgcn_s_setprio(0);
      if (mh == 0) {
#pragma unroll
        for (int n = 0; n < 4; ++n)
          bl[n] = *(const short8*)(Lb + 24576 + wc * 2048 + n * 512 + rdoff);
      }
      __builtin_amdgcn_s_setprio(1);
#pragma unroll
      for (int i = 0; i < 4; ++i)
#pragma unroll
        for (int n = 0; n < 4; ++n)
          acc[mh * 4 + i][n] = mfma16(ah[i], bl[n], acc[mh * 4 + i][n]);
      __builtin_amdgcn_s_setprio(0);
#pragma unroll
      for (int i = 0; i < 4; ++i)
        al[i] = *(const short8*)(Lb + 8192 + ab + i * 512);
      __builtin_amdgcn_s_setprio(1);
#pragma unroll
      for (int i = 0; i < 4; ++i)
#pragma unroll
        for (int n = 0; n < 4; ++n)
          acc[mh * 4 + i][n] = mfma16(al[i], bh[n], acc[mh * 4 + i][n]);
      __builtin_amdgcn_s_setprio(0);
    }
  }
#undef BAR

  __syncthreads();  // K-loop fully retired; LDS free for epilogue reuse

  // ---- epilogue: bias + gelu (in place), halt partial dot
  float bv[4], hwv[4];
#pragma unroll
  for (int ni = 0; ni < 4; ++ni) {
    int col = bn0 + wc * 64 + ni * 16 + r16;
    bv[ni] = bias[col];
    hwv[ni] = halt_w[col];
  }
  float zp[8][4];
#pragma unroll
  for (int mi = 0; mi < 8; ++mi)
#pragma unroll
    for (int j = 0; j < 4; ++j) {
      float zz = 0.0f;
#pragma unroll
      for (int ni = 0; ni < 4; ++ni) {
        float v = gelu_f(acc[mi][ni][j] + bv[ni]);
        acc[mi][ni][j] = v;
        zz += v * hwv[ni];
      }
      zp[mi][j] = zz;
    }
#pragma unroll
  for (int off = 1; off < 16; off <<= 1)
#pragma unroll
    for (int mi = 0; mi < 8; ++mi)
#pragma unroll
      for (int j = 0; j < 4; ++j) zp[mi][j] += __shfl_xor(zp[mi][j], off);
  float* zf = (float*)lds;  // [4][256]
  if (r16 == 0) {
#pragma unroll
    for (int mi = 0; mi < 8; ++mi)
#pragma unroll
      for (int j = 0; j < 4; ++j)
        zf[wc * 256 + wr * 128 + mi * 16 + g * 4 + j] = zp[mi][j];
  }
  __syncthreads();
  if (t < 256) {
    float z = zf[t] + zf[256 + t] + zf[512 + t] + zf[768 + t];
    zpart[(size_t)(bn0 >> 8) * M + bm0 + t] = z;
  }
  __syncthreads();

  // ---- hi plane repack + store
  u16* hp = lds;  // [256][256]
#pragma unroll
  for (int mi = 0; mi < 8; ++mi)
#pragma unroll
    for (int ni = 0; ni < 4; ++ni)
#pragma unroll
      for (int j = 0; j < 4; ++j)
        hp[(wr * 128 + mi * 16 + g * 4 + j) * 256 + wc * 64 + ni * 16 + r16] =
            f2bf(acc[mi][ni][j]);
  __syncthreads();
#pragma unroll
  for (int q = 0; q < 16; ++q) {
    int idx = q * 512 + t;
    int r = idx >> 5, cc = idx & 31;
    *(short8*)(Hh + (size_t)(bm0 + r) * D_DIM + bn0 + cc * 8) =
        *(const short8*)&hp[r * 256 + cc * 8];
  }
  __syncthreads();
  // ---- lo plane
#pragma unroll
  for (int mi = 0; mi < 8; ++mi)
#pragma unroll
    for (int ni = 0; ni < 4; ++ni)
#pragma unroll
      for (int j = 0; j < 4; ++j) {
        float v = acc[mi][ni][j];
        hp[(wr * 128 + mi * 16 + g * 4 + j) * 256 + wc * 64 + ni * 16 + r16] =
            f2bf(v - bf2f(f2bf(v)));
      }
  __syncthreads();
#pragma unroll
  for (int q = 0; q < 16; ++q) {
    int idx = q * 512 + t;
    int r = idx >> 5, cc = idx & 31;
    *(short8*)(Hl + (size_t)(bm0 + r) * D_DIM + bn0 + cc * 8) =
        *(const short8*)&hp[r * 256 + cc * 8];
  }
}

// ---------------- ACT scalar kernels ----------------
__global__ __launch_bounds__(256) void act_weights_kernel(
    const float* __restrict__ zpart, const float* __restrict__ halt_b,
    float* __restrict__ cum, float* __restrict__ rem, float* __restrict__ pond,
    float* __restrict__ wout, int step, int last, int M, int nblk) {
  int tok = blockIdx.x * 256 + threadIdx.x;
  float z = halt_b[0];
  for (int nb = 0; nb < nblk; ++nb) z += zpart[(size_t)nb * M + tok];
  float p = 1.0f / (1.0f + expf(-z));
  float c, r, q;
  if (step == 0) {
    c = 0.0f; r = 1.0f; q = 0.0f;
  } else {
    c = cum[tok]; r = rem[tok]; q = pond[tok];
  }
  float weight = last ? r : (((c + p) >= 0.99f) ? r : p);
  q += weight;
  c += weight;
  r = fmaxf(1.0f - c, 0.0f);
  cum[tok] = c;
  rem[tok] = r;
  pond[tok] = q;
  wout[tok] = weight;
}

// out (+)= sum_s w_s * h_s   (hi plane only: bf16 precision ample for output)
__global__ __launch_bounds__(256) void act_out_kernel(
    const u16* __restrict__ hbase, size_t pstride, const float* __restrict__ w,
    int nsteps, int accum, float* __restrict__ out, int M) {
  size_t gid = (size_t)blockIdx.x * 256 + threadIdx.x;
  int tok = (int)(gid >> 7);
  int off = ((int)gid & 127) * 8;
  size_t base = (size_t)tok * D_DIM + off;
  float o[8];
  if (accum) {
    float4 a = *(const float4*)(out + base);
    float4 b = *(const float4*)(out + base + 4);
    o[0] = a.x; o[1] = a.y; o[2] = a.z; o[3] = a.w;
    o[4] = b.x; o[5] = b.y; o[6] = b.z; o[7] = b.w;
  } else {
#pragma unroll
    for (int j = 0; j < 8; ++j) o[j] = 0.0f;
  }
  for (int s = 0; s < nsteps; ++s) {
    float ws = w[(size_t)s * M + tok];
    short8 hi = *(const short8*)(hbase + (size_t)s * pstride + base);
#pragma unroll
    for (int j = 0; j < 8; ++j) o[j] += ws * bf2f((u16)hi[j]);
  }
  *(float4*)(out + base) = make_float4(o[0], o[1], o[2], o[3]);
  *(float4*)(out + base + 4) = make_float4(o[4], o[5], o[6], o[7]);
}

__global__ __launch_bounds__(256) void ponder_reduce_kernel(
    const float* __restrict__ pond, float* __restrict__ o, int n) {
  __shared__ float sh[256];
  float a = 0.0f;
  for (int i = threadIdx.x; i < n; i += 256) a += pond[i];
  sh[threadIdx.x] = a;
  __syncthreads();
  for (int s = 128; s; s >>= 1) {
    if ((int)threadIdx.x < s) sh[threadIdx.x] += sh[threadIdx.x + s];
    __syncthreads();
  }
  if (threadIdx.x == 0) o[0] = sh[0] / (float)n;
}

extern "C" void kernel_launch(void* const* d_in, const int* in_sizes, int n_in,
                              void* d_out, int out_size, void* d_ws,
                              size_t ws_size, hipStream_t stream) {
  const float* x = (const float*)d_in[0];
  const float* layer_w = (const float*)d_in[1];
  const float* layer_b = (const float*)d_in[2];
  const float* halt_w = (const float*)d_in[3];
  const float* halt_b = (const float*)d_in[4];
  float* out = (float*)d_out;

  const int D = D_DIM;
  const int M = in_sizes[0] / D;        // 16384
  const int L = in_sizes[1] / (D * D);  // 4
  const size_t MD = (size_t)M * D, DD = (size_t)D * D;

  char* ws = (char*)d_ws;
  size_t off = 0;
  auto alloc = [&](size_t bytes) {
    void* p = ws + off;
    off += (bytes + 255) & ~(size_t)255;
    return p;
  };
  u16* Wsplit = (u16*)alloc((size_t)L * 2 * DD * sizeof(u16));  // hi | lo
  float* zpart = (float*)alloc(4 * (size_t)M * 4);
  float* wbuf = (float*)alloc((size_t)L * M * 4);
  float* cum = (float*)alloc((size_t)M * 4);
  float* rem = (float*)alloc((size_t)M * 4);
  float* pond = (float*)alloc((size_t)M * 4);

  const size_t planeElems = 2 * MD;          // hi + lo (u16)
  const size_t planeBytes = planeElems * 2;  // 67.1 MB
  const bool deferred = (off + (size_t)(L + 1) * planeBytes) <= ws_size;
  const int nbufs = deferred ? (L + 1) : 2;
  u16* planes = (u16*)alloc((size_t)nbufs * planeBytes);

  hipFuncSetAttribute((const void*)gemm_act_kernel,
                      hipFuncAttributeMaxDynamicSharedMemorySize, 131072);

  prep_x_kernel<<<(unsigned)(MD / 1024), 256, 0, stream>>>(x, planes,
                                                           planes + MD);
  prep_w_kernel<<<dim3(D / 64, D / 64, L), 256, 0, stream>>>(
      layer_w, Wsplit, Wsplit + (size_t)L * DD);

  for (int s = 0; s < L; ++s) {
    u16* pin = planes + (size_t)(deferred ? s : (s & 1)) * planeElems;
    u16* pout =
        planes + (size_t)(deferred ? (s + 1) : ((s + 1) & 1)) * planeElems;
    gemm_act_kernel<<<dim3(M / 256 * (D / 256)), 512, 131072, stream>>>(
        pin, pin + MD, Wsplit + (size_t)s * DD, Wsplit + (size_t)(L + s) * DD,
        layer_b + (size_t)s * D, halt_w, pout, pout + MD, zpart, M);
    act_weights_kernel<<<M / 256, 256, 0, stream>>>(
        zpart, halt_b, cum, rem, pond, wbuf + (size_t)s * M, s,
        (s == L - 1) ? 1 : 0, M, D / 256);
    if (!deferred)
      act_out_kernel<<<(unsigned)(MD / 2048), 256, 0, stream>>>(
          pout, 0, wbuf + (size_t)s * M, 1, (s > 0) ? 1 : 0, out, M);
  }
  if (deferred)
    act_out_kernel<<<(unsigned)(MD / 2048), 256, 0, stream>>>(
        planes + planeElems, planeElems, wbuf, L, 0, out, M);
  ponder_reduce_kernel<<<1, 256, 0, stream>>>(pond, out + MD, M);
}

// Round 6
// 567.001 us; speedup vs baseline: 2.2207x; 1.0549x over previous
//
#include <hip/hip_runtime.h>

typedef __attribute__((ext_vector_type(8))) short short8;
typedef __attribute__((ext_vector_type(4))) float f32x4;
typedef __attribute__((ext_vector_type(4))) unsigned short u16x4;
typedef unsigned short u16;

#define D_DIM 1024
#define NKT 32  // K / 32, all 4 planes fused per K-slice

__device__ __forceinline__ u16 f2bf(float f) {
  unsigned u = __builtin_bit_cast(unsigned, f);
  u += 0x7fffu + ((u >> 16) & 1u);
  return (u16)(u >> 16);
}
__device__ __forceinline__ float bf2f(u16 b) {
  return __builtin_bit_cast(float, ((unsigned)b) << 16);
}
__device__ __forceinline__ float gelu_f(float x) {
  float i = 0.7978845608028654f * (x + 0.044715f * x * x * x);
  float ex = __builtin_amdgcn_exp2f(i * 2.885390081777927f);  // e^{2i}
  float th = 1.0f - 2.0f * __builtin_amdgcn_rcpf(ex + 1.0f);
  return 0.5f * x * (1.0f + th);
}
__device__ __forceinline__ f32x4 mfma16(short8 a, short8 b, f32x4 c) {
  return __builtin_amdgcn_mfma_f32_16x16x32_bf16(a, b, c, 0, 0, 0);
}
__device__ __forceinline__ void glds16(const u16* g, const u16* l) {
  __builtin_amdgcn_global_load_lds(
      (const __attribute__((address_space(1))) void*)g,
      (__attribute__((address_space(3))) void*)l, 16, 0, 0);
}

// ---------------- prep kernels ----------------
__global__ __launch_bounds__(256) void prep_w_kernel(
    const float* __restrict__ W, u16* __restrict__ Wth, u16* __restrict__ Wtl) {
  __shared__ float tile[64][65];
  const int t = threadIdx.x;
  const int k0 = blockIdx.x * 64, n0 = blockIdx.y * 64;
  const size_t lbase = (size_t)blockIdx.z * D_DIM * D_DIM;
#pragma unroll
  for (int j = 0; j < 16; ++j) {
    int idx = t + 256 * j;
    int r = idx >> 6, c = idx & 63;
    tile[r][c] = W[lbase + (size_t)(k0 + r) * D_DIM + (n0 + c)];
  }
  __syncthreads();
#pragma unroll
  for (int j = 0; j < 16; ++j) {
    int idx = t + 256 * j;
    int r = idx >> 6, c = idx & 63;
    float f = tile[c][r];
    u16 hb = f2bf(f);
    u16 lb = f2bf(f - bf2f(hb));
    size_t oidx = lbase + (size_t)(n0 + r) * D_DIM + (k0 + c);
    Wth[oidx] = hb;
    Wtl[oidx] = lb;
  }
}

__global__ __launch_bounds__(256) void prep_x_kernel(
    const float* __restrict__ x, u16* __restrict__ xh, u16* __restrict__ xl) {
  size_t i = ((size_t)blockIdx.x * 256 + threadIdx.x) * 4;
  const float4 v = *(const float4*)(x + i);
  const float fv[4] = {v.x, v.y, v.z, v.w};
  u16x4 h4, l4;
#pragma unroll
  for (int c = 0; c < 4; ++c) {
    u16 hb = f2bf(fv[c]);
    h4[c] = hb;
    l4[c] = f2bf(fv[c] - bf2f(hb));
  }
  *(u16x4*)(xh + i) = h4;
  *(u16x4*)(xl + i) = l4;
}

// ---------------- 256x256 phase-disciplined GEMM + ACT epilogue ----------
// LDS per buffer (32768 u16): Ah[256][32] | Al | Bh | Bl, each 8192 u16.
// Within a plane, 16B slot s of row r holds global k-chunk s ^ ((r>>1)&3):
// -> frag reads cover all 8 bank-quads uniformly (conflict-free), and the
//    glds source per 4-lane quad is one aligned 64B row segment (coalesced).
__global__ __launch_bounds__(512, 2) void gemm_act_kernel(
    const u16* __restrict__ Ahp, const u16* __restrict__ Alp,
    const u16* __restrict__ Bhp, const u16* __restrict__ Blp,
    const float* __restrict__ bias, const float* __restrict__ halt_w,
    u16* __restrict__ Hh, u16* __restrict__ Hl, float* __restrict__ zpart,
    int M, int writeLo) {
  extern __shared__ u16 lds[];  // 2 x 64 KiB
  const int t = threadIdx.x;
  const int bid = blockIdx.x;                  // 256 blocks
  const int wg = (bid & 7) * 32 + (bid >> 3);  // XCD-chunked, bijective
  const int bn0 = (wg & 3) * 256;
  const int bm0 = (wg >> 2) * 256;
  const int lane = t & 63, wid = t >> 6;
  const int wr = wid >> 2, wc = wid & 3;
  const int g = lane >> 4, r16 = lane & 15;

  // staging geometry: unit j of wave = 1024B = 16 rows x 64B of one plane
  const int lrow = lane >> 2;                       // row within 16-row unit
  const int lchunk = (lane & 3) ^ ((lane >> 3) & 3);  // global k-chunk
  const u16* sbase[8];
  int ldsoff[8];
#pragma unroll
  for (int j = 0; j < 8; ++j) {
    const int p = j >> 1;               // plane: 0 Ah, 1 Al, 2 Bh, 3 Bl
    const int v = wid + 8 * (j & 1);    // 16-row group 0..15
    const u16* gp = (p == 0) ? Ahp : (p == 1) ? Alp : (p == 2) ? Bhp : Blp;
    const int r0 = (p < 2) ? bm0 : bn0;
    sbase[j] = gp + (size_t)(r0 + 16 * v + lrow) * D_DIM + lchunk * 8;
    ldsoff[j] = p * 8192 + v * 512 + lane * 8;
  }

  // fragment read offsets (u16): row*32 + (g ^ ((r16>>1)&3))*8
  const int fsw = ((g ^ (r16 >> 1)) & 3) * 8;
  const int arow0 = (wr * 128 + r16) * 32 + fsw;
  const int brow0 = 16384 + (wc * 64 + r16) * 32 + fsw;

  f32x4 acc[8][4];
#pragma unroll
  for (int i = 0; i < 8; ++i)
#pragma unroll
    for (int j = 0; j < 4; ++j) acc[i][j] = (f32x4)0.0f;

  // prologue: stage tile 0 fully into buf 0
#pragma unroll
  for (int j = 0; j < 8; ++j) glds16(sbase[j], lds + ldsoff[j]);

#pragma unroll 1
  for (int kt = 0; kt < NKT; ++kt) {
    // gate: my glds for tile kt retired; barrier makes it global
    asm volatile("s_waitcnt vmcnt(0)" ::: "memory");
    __builtin_amdgcn_s_barrier();
    asm volatile("" ::: "memory");
    const u16* Lb = lds + ((kt & 1) << 15);
    short8 ah[4], al[4], bh[4], bl[4];
    // ---- P0: frag reads (mh=0 A + all B) + stage A-half of kt+1
#pragma unroll
    for (int i = 0; i < 4; ++i) {
      ah[i] = *(const short8*)(Lb + arow0 + i * 512);
      al[i] = *(const short8*)(Lb + 8192 + arow0 + i * 512);
      bh[i] = *(const short8*)(Lb + brow0 + i * 512);
      bl[i] = *(const short8*)(Lb + 8192 + brow0 + i * 512);
    }
    if (kt + 1 < NKT) {
      const int k0 = (kt + 1) << 5;
      u16* db = lds + (((kt + 1) & 1) << 15);
#pragma unroll
      for (int j = 0; j < 4; ++j) glds16(sbase[j] + k0, db + ldsoff[j]);
    }
    asm volatile("" ::: "memory");
    __builtin_amdgcn_s_barrier();
    asm volatile("" ::: "memory");
    __builtin_amdgcn_s_setprio(1);
#pragma unroll
    for (int i = 0; i < 4; ++i)
#pragma unroll
      for (int n = 0; n < 4; ++n) acc[i][n] = mfma16(ah[i], bh[n], acc[i][n]);
#pragma unroll
    for (int i = 0; i < 4; ++i)
#pragma unroll
      for (int n = 0; n < 4; ++n) acc[i][n] = mfma16(ah[i], bl[n], acc[i][n]);
#pragma unroll
    for (int i = 0; i < 4; ++i)
#pragma unroll
      for (int n = 0; n < 4; ++n) acc[i][n] = mfma16(al[i], bh[n], acc[i][n]);
    __builtin_amdgcn_s_setprio(0);
    // ---- P1: frag reads (mh=1 A) + stage B-half of kt+1
#pragma unroll
    for (int i = 0; i < 4; ++i) {
      ah[i] = *(const short8*)(Lb + arow0 + (4 + i) * 512);
      al[i] = *(const short8*)(Lb + 8192 + arow0 + (4 + i) * 512);
    }
    if (kt + 1 < NKT) {
      const int k0 = (kt + 1) << 5;
      u16* db = lds + (((kt + 1) & 1) << 15);
#pragma unroll
      for (int j = 4; j < 8; ++j) glds16(sbase[j] + k0, db + ldsoff[j]);
    }
    asm volatile("" ::: "memory");
    __builtin_amdgcn_s_barrier();
    asm volatile("" ::: "memory");
    __builtin_amdgcn_s_setprio(1);
#pragma unroll
    for (int i = 0; i < 4; ++i)
#pragma unroll
      for (int n = 0; n < 4; ++n)
        acc[4 + i][n] = mfma16(ah[i], bh[n], acc[4 + i][n]);
#pragma unroll
    for (int i = 0; i < 4; ++i)
#pragma unroll
      for (int n = 0; n < 4; ++n)
        acc[4 + i][n] = mfma16(ah[i], bl[n], acc[4 + i][n]);
#pragma unroll
    for (int i = 0; i < 4; ++i)
#pragma unroll
      for (int n = 0; n < 4; ++n)
        acc[4 + i][n] = mfma16(al[i], bh[n], acc[4 + i][n]);
    __builtin_amdgcn_s_setprio(0);
  }

  __syncthreads();  // K-loop retired; LDS free for epilogue reuse

  // ---- epilogue: bias + gelu (in place), halt partial dot
  float bv[4], hwv[4];
#pragma unroll
  for (int ni = 0; ni < 4; ++ni) {
    int col = bn0 + wc * 64 + ni * 16 + r16;
    bv[ni] = bias[col];
    hwv[ni] = halt_w[col];
  }
  float zp[8][4];
#pragma unroll
  for (int mi = 0; mi < 8; ++mi)
#pragma unroll
    for (int j = 0; j < 4; ++j) {
      float zz = 0.0f;
#pragma unroll
      for (int ni = 0; ni < 4; ++ni) {
        float v = gelu_f(acc[mi][ni][j] + bv[ni]);
        acc[mi][ni][j] = v;
        zz += v * hwv[ni];
      }
      zp[mi][j] = zz;
    }
#pragma unroll
  for (int off = 1; off < 16; off <<= 1)
#pragma unroll
    for (int mi = 0; mi < 8; ++mi)
#pragma unroll
      for (int j = 0; j < 4; ++j) zp[mi][j] += __shfl_xor(zp[mi][j], off);
  float* zf = (float*)lds;  // [4][256]
  if (r16 == 0) {
#pragma unroll
    for (int mi = 0; mi < 8; ++mi)
#pragma unroll
      for (int j = 0; j < 4; ++j)
        zf[wc * 256 + wr * 128 + mi * 16 + g * 4 + j] = zp[mi][j];
  }
  __syncthreads();
  if (t < 256) {
    float z = zf[t] + zf[256 + t] + zf[512 + t] + zf[768 + t];
    zpart[(size_t)(bn0 >> 8) * M + bm0 + t] = z;
  }
  __syncthreads();

  // ---- hi plane repack + store
  u16* hp = lds;  // [256][256]
#pragma unroll
  for (int mi = 0; mi < 8; ++mi)
#pragma unroll
    for (int ni = 0; ni < 4; ++ni)
#pragma unroll
      for (int j = 0; j < 4; ++j)
        hp[(wr * 128 + mi * 16 + g * 4 + j) * 256 + wc * 64 + ni * 16 + r16] =
            f2bf(acc[mi][ni][j]);
  __syncthreads();
#pragma unroll
  for (int q = 0; q < 16; ++q) {
    int idx = q * 512 + t;
    int r = idx >> 5, cc = idx & 31;
    *(short8*)(Hh + (size_t)(bm0 + r) * D_DIM + bn0 + cc * 8) =
        *(const short8*)&hp[r * 256 + cc * 8];
  }
  // ---- lo plane (skipped for the last layer: never consumed)
  if (writeLo) {
    __syncthreads();
#pragma unroll
    for (int mi = 0; mi < 8; ++mi)
#pragma unroll
      for (int ni = 0; ni < 4; ++ni)
#pragma unroll
        for (int j = 0; j < 4; ++j) {
          float v = acc[mi][ni][j];
          hp[(wr * 128 + mi * 16 + g * 4 + j) * 256 + wc * 64 + ni * 16 +
             r16] = f2bf(v - bf2f(f2bf(v)));
        }
    __syncthreads();
#pragma unroll
    for (int q = 0; q < 16; ++q) {
      int idx = q * 512 + t;
      int r = idx >> 5, cc = idx & 31;
      *(short8*)(Hl + (size_t)(bm0 + r) * D_DIM + bn0 + cc * 8) =
          *(const short8*)&hp[r * 256 + cc * 8];
    }
  }
}

// ---------------- ACT scalar kernels ----------------
__global__ __launch_bounds__(256) void act_weights_kernel(
    const float* __restrict__ zpart, const float* __restrict__ halt_b,
    float* __restrict__ cum, float* __restrict__ rem, float* __restrict__ pond,
    float* __restrict__ wout, int step, int last, int M, int nblk) {
  int tok = blockIdx.x * 256 + threadIdx.x;
  float z = halt_b[0];
  for (int nb = 0; nb < nblk; ++nb) z += zpart[(size_t)nb * M + tok];
  float p = 1.0f / (1.0f + expf(-z));
  float c, r, q;
  if (step == 0) {
    c = 0.0f; r = 1.0f; q = 0.0f;
  } else {
    c = cum[tok]; r = rem[tok]; q = pond[tok];
  }
  float weight = last ? r : (((c + p) >= 0.99f) ? r : p);
  q += weight;
  c += weight;
  r = fmaxf(1.0f - c, 0.0f);
  cum[tok] = c;
  rem[tok] = r;
  pond[tok] = q;
  wout[tok] = weight;
}

// out (+)= sum_s w_s * h_s   (hi plane only: bf16 precision ample for output)
__global__ __launch_bounds__(256) void act_out_kernel(
    const u16* __restrict__ hbase, size_t pstride, const float* __restrict__ w,
    int nsteps, int accum, float* __restrict__ out, int M) {
  size_t gid = (size_t)blockIdx.x * 256 + threadIdx.x;
  int tok = (int)(gid >> 7);
  int off = ((int)gid & 127) * 8;
  size_t base = (size_t)tok * D_DIM + off;
  float o[8];
  if (accum) {
    float4 a = *(const float4*)(out + base);
    float4 b = *(const float4*)(out + base + 4);
    o[0] = a.x; o[1] = a.y; o[2] = a.z; o[3] = a.w;
    o[4] = b.x; o[5] = b.y; o[6] = b.z; o[7] = b.w;
  } else {
#pragma unroll
    for (int j = 0; j < 8; ++j) o[j] = 0.0f;
  }
  for (int s = 0; s < nsteps; ++s) {
    float ws = w[(size_t)s * M + tok];
    short8 hi = *(const short8*)(hbase + (size_t)s * pstride + base);
#pragma unroll
    for (int j = 0; j < 8; ++j) o[j] += ws * bf2f((u16)hi[j]);
  }
  *(float4*)(out + base) = make_float4(o[0], o[1], o[2], o[3]);
  *(float4*)(out + base + 4) = make_float4(o[4], o[5], o[6], o[7]);
}

__global__ __launch_bounds__(256) void ponder_reduce_kernel(
    const float* __restrict__ pond, float* __restrict__ o, int n) {
  __shared__ float sh[256];
  float a = 0.0f;
  for (int i = threadIdx.x; i < n; i += 256) a += pond[i];
  sh[threadIdx.x] = a;
  __syncthreads();
  for (int s = 128; s; s >>= 1) {
    if ((int)threadIdx.x < s) sh[threadIdx.x] += sh[threadIdx.x + s];
    __syncthreads();
  }
  if (threadIdx.x == 0) o[0] = sh[0] / (float)n;
}

extern "C" void kernel_launch(void* const* d_in, const int* in_sizes, int n_in,
                              void* d_out, int out_size, void* d_ws,
                              size_t ws_size, hipStream_t stream) {
  const float* x = (const float*)d_in[0];
  const float* layer_w = (const float*)d_in[1];
  const float* layer_b = (const float*)d_in[2];
  const float* halt_w = (const float*)d_in[3];
  const float* halt_b = (const float*)d_in[4];
  float* out = (float*)d_out;

  const int D = D_DIM;
  const int M = in_sizes[0] / D;        // 16384
  const int L = in_sizes[1] / (D * D);  // 4
  const size_t MD = (size_t)M * D, DD = (size_t)D * D;

  char* ws = (char*)d_ws;
  size_t off = 0;
  auto alloc = [&](size_t bytes) {
    void* p = ws + off;
    off += (bytes + 255) & ~(size_t)255;
    return p;
  };
  u16* Wsplit = (u16*)alloc((size_t)L * 2 * DD * sizeof(u16));  // hi | lo
  float* zpart = (float*)alloc(4 * (size_t)M * 4);
  float* wbuf = (float*)alloc((size_t)L * M * 4);
  float* cum = (float*)alloc((size_t)M * 4);
  float* rem = (float*)alloc((size_t)M * 4);
  float* pond = (float*)alloc((size_t)M * 4);

  const size_t planeElems = 2 * MD;          // hi + lo (u16)
  const size_t planeBytes = planeElems * 2;  // 67.1 MB
  const bool deferred = (off + (size_t)(L + 1) * planeBytes) <= ws_size;
  const int nbufs = deferred ? (L + 1) : 2;
  u16* planes = (u16*)alloc((size_t)nbufs * planeBytes);

  hipFuncSetAttribute((const void*)gemm_act_kernel,
                      hipFuncAttributeMaxDynamicSharedMemorySize, 131072);

  prep_x_kernel<<<(unsigned)(MD / 1024), 256, 0, stream>>>(x, planes,
                                                           planes + MD);
  prep_w_kernel<<<dim3(D / 64, D / 64, L), 256, 0, stream>>>(
      layer_w, Wsplit, Wsplit + (size_t)L * DD);

  for (int s = 0; s < L; ++s) {
    u16* pin = planes + (size_t)(deferred ? s : (s & 1)) * planeElems;
    u16* pout =
        planes + (size_t)(deferred ? (s + 1) : ((s + 1) & 1)) * planeElems;
    gemm_act_kernel<<<dim3(M / 256 * (D / 256)), 512, 131072, stream>>>(
        pin, pin + MD, Wsplit + (size_t)s * DD, Wsplit + (size_t)(L + s) * DD,
        layer_b + (size_t)s * D, halt_w, pout, pout + MD, zpart, M,
        (s < L - 1) ? 1 : 0);
    act_weights_kernel<<<M / 256, 256, 0, stream>>>(
        zpart, halt_b, cum, rem, pond, wbuf + (size_t)s * M, s,
        (s == L - 1) ? 1 : 0, M, D / 256);
    if (!deferred)
      act_out_kernel<<<(unsigned)(MD / 2048), 256, 0, stream>>>(
          pout, 0, wbuf + (size_t)s * M, 1, (s > 0) ? 1 : 0, out, M);
  }
  if (deferred)
    act_out_kernel<<<(unsigned)(MD / 2048), 256, 0, stream>>>(
        planes + planeElems, planeElems, wbuf, L, 0, out, M);
  ponder_reduce_kernel<<<1, 256, 0, stream>>>(pond, out + MD, M);
}

// Round 7
// 565.282 us; speedup vs baseline: 2.2275x; 1.0030x over previous
//
#include <hip/hip_runtime.h>

typedef __attribute__((ext_vector_type(8))) short short8;
typedef __attribute__((ext_vector_type(4))) float f32x4;
typedef __attribute__((ext_vector_type(4))) unsigned short u16x4;
typedef unsigned short u16;

#define D_DIM 1024
#define NKT 32  // K / 32, all 4 planes fused per K-slice

__device__ __forceinline__ u16 f2bf(float f) {
  unsigned u = __builtin_bit_cast(unsigned, f);
  u += 0x7fffu + ((u >> 16) & 1u);
  return (u16)(u >> 16);
}
__device__ __forceinline__ float bf2f(u16 b) {
  return __builtin_bit_cast(float, ((unsigned)b) << 16);
}
__device__ __forceinline__ float gelu_f(float x) {
  float i = 0.7978845608028654f * (x + 0.044715f * x * x * x);
  float ex = __builtin_amdgcn_exp2f(i * 2.885390081777927f);  // e^{2i}
  float th = 1.0f - 2.0f * __builtin_amdgcn_rcpf(ex + 1.0f);
  return 0.5f * x * (1.0f + th);
}
__device__ __forceinline__ f32x4 mfma16(short8 a, short8 b, f32x4 c) {
  return __builtin_amdgcn_mfma_f32_16x16x32_bf16(a, b, c, 0, 0, 0);
}
__device__ __forceinline__ void glds16(const u16* g, const u16* l) {
  __builtin_amdgcn_global_load_lds(
      (const __attribute__((address_space(1))) void*)g,
      (__attribute__((address_space(3))) void*)l, 16, 0, 0);
}

// ---------------- prep kernels ----------------
__global__ __launch_bounds__(256) void prep_w_kernel(
    const float* __restrict__ W, u16* __restrict__ Wth, u16* __restrict__ Wtl) {
  __shared__ float tile[64][65];
  const int t = threadIdx.x;
  const int k0 = blockIdx.x * 64, n0 = blockIdx.y * 64;
  const size_t lbase = (size_t)blockIdx.z * D_DIM * D_DIM;
#pragma unroll
  for (int j = 0; j < 16; ++j) {
    int idx = t + 256 * j;
    int r = idx >> 6, c = idx & 63;
    tile[r][c] = W[lbase + (size_t)(k0 + r) * D_DIM + (n0 + c)];
  }
  __syncthreads();
#pragma unroll
  for (int j = 0; j < 16; ++j) {
    int idx = t + 256 * j;
    int r = idx >> 6, c = idx & 63;
    float f = tile[c][r];
    u16 hb = f2bf(f);
    u16 lb = f2bf(f - bf2f(hb));
    size_t oidx = lbase + (size_t)(n0 + r) * D_DIM + (k0 + c);
    Wth[oidx] = hb;
    Wtl[oidx] = lb;
  }
}

__global__ __launch_bounds__(256) void prep_x_kernel(
    const float* __restrict__ x, u16* __restrict__ xh, u16* __restrict__ xl) {
  size_t i = ((size_t)blockIdx.x * 256 + threadIdx.x) * 4;
  const float4 v = *(const float4*)(x + i);
  const float fv[4] = {v.x, v.y, v.z, v.w};
  u16x4 h4, l4;
#pragma unroll
  for (int c = 0; c < 4; ++c) {
    u16 hb = f2bf(fv[c]);
    h4[c] = hb;
    l4[c] = f2bf(fv[c] - bf2f(hb));
  }
  *(u16x4*)(xh + i) = h4;
  *(u16x4*)(xl + i) = l4;
}

// ---------------- 256x256 drift-scheduled GEMM + ACT epilogue ----------
// LDS per buffer (32768 u16): Ah[256][32] | Al | Bh | Bl, each 8192 u16.
// Within a plane, 16B slot s of row r holds global k-chunk s ^ ((r>>1)&3):
// frag reads cover all 8 bank-quads uniformly; glds source per 4-lane quad
// is one aligned 64B row segment (coalesced).
// ONE barrier per K-tile; tile interior is barrier-free so the compiler's
// counted lgkmcnt + natural wave drift co-feed the LDS and MFMA pipes.
__global__ __launch_bounds__(512, 2) void gemm_act_kernel(
    const u16* __restrict__ Ahp, const u16* __restrict__ Alp,
    const u16* __restrict__ Bhp, const u16* __restrict__ Blp,
    const float* __restrict__ bias, const float* __restrict__ halt_w,
    u16* __restrict__ Hh, u16* __restrict__ Hl, float* __restrict__ zpart,
    int M, int writeLo) {
  extern __shared__ u16 lds[];  // 2 x 64 KiB
  const int t = threadIdx.x;
  const int bid = blockIdx.x;                  // 256 blocks
  const int wg = (bid & 7) * 32 + (bid >> 3);  // XCD-chunked, bijective
  const int bn0 = (wg & 3) * 256;
  const int bm0 = (wg >> 2) * 256;
  const int lane = t & 63, wid = t >> 6;
  const int wr = wid >> 2, wc = wid & 3;
  const int g = lane >> 4, r16 = lane & 15;

  // staging geometry: unit j of wave = 1024B = 16 rows x 64B of one plane
  const int lrow = lane >> 2;                         // row within 16-row unit
  const int lchunk = (lane & 3) ^ ((lane >> 3) & 3);  // global k-chunk
  const u16* sbase[8];
  int ldsoff[8];
#pragma unroll
  for (int j = 0; j < 8; ++j) {
    const int p = j >> 1;             // plane: 0 Ah, 1 Al, 2 Bh, 3 Bl
    const int v = wid + 8 * (j & 1);  // 16-row group 0..15
    const u16* gp = (p == 0) ? Ahp : (p == 1) ? Alp : (p == 2) ? Bhp : Blp;
    const int r0 = (p < 2) ? bm0 : bn0;
    sbase[j] = gp + (size_t)(r0 + 16 * v + lrow) * D_DIM + lchunk * 8;
    ldsoff[j] = p * 8192 + v * 512 + lane * 8;
  }

  // fragment read offsets (u16): row*32 + (g ^ ((r16>>1)&3))*8
  const int fsw = ((g ^ (r16 >> 1)) & 3) * 8;
  const int arow0 = (wr * 128 + r16) * 32 + fsw;
  const int brow0 = 16384 + (wc * 64 + r16) * 32 + fsw;

  f32x4 acc[8][4];
#pragma unroll
  for (int i = 0; i < 8; ++i)
#pragma unroll
    for (int j = 0; j < 4; ++j) acc[i][j] = (f32x4)0.0f;

  // prologue: stage tile 0 fully into buf 0
#pragma unroll
  for (int j = 0; j < 8; ++j) glds16(sbase[j], lds + ldsoff[j]);

#pragma unroll 1
  for (int kt = 0; kt < NKT; ++kt) {
    // gate: my glds for tile kt retired; barrier makes all staging visible
    // and proves every wave is done reading buf[(kt+1)&1] (consumed by tile
    // kt-1's MFMAs, which precede this barrier in every wave).
    asm volatile("s_waitcnt vmcnt(0)" ::: "memory");
    __builtin_amdgcn_s_barrier();
    asm volatile("" ::: "memory");
    const u16* Lb = lds + ((kt & 1) << 15);
    // prefetch tile kt+1 into the other buffer (issued early, drains by the
    // next gate a full tile later)
    if (kt + 1 < NKT) {
      const int k0 = (kt + 1) << 5;
      u16* db = lds + (((kt + 1) & 1) << 15);
#pragma unroll
      for (int j = 0; j < 8; ++j) glds16(sbase[j] + k0, db + ldsoff[j]);
    }
    // ---- interleaved frag-reads / MFMA clusters (no barriers inside) ----
    short8 ah[4], al[4], bh[4], bl[4], ah2[4], al2[4];
#pragma unroll
    for (int i = 0; i < 4; ++i) {
      ah[i] = *(const short8*)(Lb + arow0 + i * 512);
      bh[i] = *(const short8*)(Lb + brow0 + i * 512);
    }
    __builtin_amdgcn_s_setprio(1);
#pragma unroll
    for (int i = 0; i < 4; ++i)
#pragma unroll
      for (int n = 0; n < 4; ++n) acc[i][n] = mfma16(ah[i], bh[n], acc[i][n]);
    __builtin_amdgcn_s_setprio(0);
#pragma unroll
    for (int i = 0; i < 4; ++i) {
      al[i] = *(const short8*)(Lb + 8192 + arow0 + i * 512);
      bl[i] = *(const short8*)(Lb + 8192 + brow0 + i * 512);
    }
    __builtin_amdgcn_s_setprio(1);
#pragma unroll
    for (int i = 0; i < 4; ++i)
#pragma unroll
      for (int n = 0; n < 4; ++n) acc[i][n] = mfma16(ah[i], bl[n], acc[i][n]);
#pragma unroll
    for (int i = 0; i < 4; ++i)
#pragma unroll
      for (int n = 0; n < 4; ++n) acc[i][n] = mfma16(al[i], bh[n], acc[i][n]);
    __builtin_amdgcn_s_setprio(0);
#pragma unroll
    for (int i = 0; i < 4; ++i) {
      ah2[i] = *(const short8*)(Lb + arow0 + (4 + i) * 512);
      al2[i] = *(const short8*)(Lb + 8192 + arow0 + (4 + i) * 512);
    }
    __builtin_amdgcn_s_setprio(1);
#pragma unroll
    for (int i = 0; i < 4; ++i)
#pragma unroll
      for (int n = 0; n < 4; ++n)
        acc[4 + i][n] = mfma16(ah2[i], bh[n], acc[4 + i][n]);
#pragma unroll
    for (int i = 0; i < 4; ++i)
#pragma unroll
      for (int n = 0; n < 4; ++n)
        acc[4 + i][n] = mfma16(ah2[i], bl[n], acc[4 + i][n]);
#pragma unroll
    for (int i = 0; i < 4; ++i)
#pragma unroll
      for (int n = 0; n < 4; ++n)
        acc[4 + i][n] = mfma16(al2[i], bh[n], acc[4 + i][n]);
    __builtin_amdgcn_s_setprio(0);
  }

  __syncthreads();  // K-loop retired; LDS free for epilogue reuse

  // ---- epilogue: bias + gelu (in place), halt partial dot
  float bv[4], hwv[4];
#pragma unroll
  for (int ni = 0; ni < 4; ++ni) {
    int col = bn0 + wc * 64 + ni * 16 + r16;
    bv[ni] = bias[col];
    hwv[ni] = halt_w[col];
  }
  float zp[8][4];
#pragma unroll
  for (int mi = 0; mi < 8; ++mi)
#pragma unroll
    for (int j = 0; j < 4; ++j) {
      float zz = 0.0f;
#pragma unroll
      for (int ni = 0; ni < 4; ++ni) {
        float v = gelu_f(acc[mi][ni][j] + bv[ni]);
        acc[mi][ni][j] = v;
        zz += v * hwv[ni];
      }
      zp[mi][j] = zz;
    }
#pragma unroll
  for (int off = 1; off < 16; off <<= 1)
#pragma unroll
    for (int mi = 0; mi < 8; ++mi)
#pragma unroll
      for (int j = 0; j < 4; ++j) zp[mi][j] += __shfl_xor(zp[mi][j], off);
  float* zf = (float*)lds;  // [4][256]
  if (r16 == 0) {
#pragma unroll
    for (int mi = 0; mi < 8; ++mi)
#pragma unroll
      for (int j = 0; j < 4; ++j)
        zf[wc * 256 + wr * 128 + mi * 16 + g * 4 + j] = zp[mi][j];
  }
  __syncthreads();
  if (t < 256) {
    float z = zf[t] + zf[256 + t] + zf[512 + t] + zf[768 + t];
    zpart[(size_t)(bn0 >> 8) * M + bm0 + t] = z;
  }
  __syncthreads();

  // ---- hi plane repack + store
  u16* hp = lds;  // [256][256]
#pragma unroll
  for (int mi = 0; mi < 8; ++mi)
#pragma unroll
    for (int ni = 0; ni < 4; ++ni)
#pragma unroll
      for (int j = 0; j < 4; ++j)
        hp[(wr * 128 + mi * 16 + g * 4 + j) * 256 + wc * 64 + ni * 16 + r16] =
            f2bf(acc[mi][ni][j]);
  __syncthreads();
#pragma unroll
  for (int q = 0; q < 16; ++q) {
    int idx = q * 512 + t;
    int r = idx >> 5, cc = idx & 31;
    *(short8*)(Hh + (size_t)(bm0 + r) * D_DIM + bn0 + cc * 8) =
        *(const short8*)&hp[r * 256 + cc * 8];
  }
  // ---- lo plane (skipped for the last layer: never consumed)
  if (writeLo) {
    __syncthreads();
#pragma unroll
    for (int mi = 0; mi < 8; ++mi)
#pragma unroll
      for (int ni = 0; ni < 4; ++ni)
#pragma unroll
        for (int j = 0; j < 4; ++j) {
          float v = acc[mi][ni][j];
          hp[(wr * 128 + mi * 16 + g * 4 + j) * 256 + wc * 64 + ni * 16 +
             r16] = f2bf(v - bf2f(f2bf(v)));
        }
    __syncthreads();
#pragma unroll
    for (int q = 0; q < 16; ++q) {
      int idx = q * 512 + t;
      int r = idx >> 5, cc = idx & 31;
      *(short8*)(Hl + (size_t)(bm0 + r) * D_DIM + bn0 + cc * 8) =
          *(const short8*)&hp[r * 256 + cc * 8];
    }
  }
}

// ---------------- ACT scalar kernels ----------------
__global__ __launch_bounds__(256) void act_weights_kernel(
    const float* __restrict__ zpart, const float* __restrict__ halt_b,
    float* __restrict__ cum, float* __restrict__ rem, float* __restrict__ pond,
    float* __restrict__ wout, int step, int last, int M, int nblk) {
  int tok = blockIdx.x * 256 + threadIdx.x;
  float z = halt_b[0];
  for (int nb = 0; nb < nblk; ++nb) z += zpart[(size_t)nb * M + tok];
  float p = 1.0f / (1.0f + expf(-z));
  float c, r, q;
  if (step == 0) {
    c = 0.0f; r = 1.0f; q = 0.0f;
  } else {
    c = cum[tok]; r = rem[tok]; q = pond[tok];
  }
  float weight = last ? r : (((c + p) >= 0.99f) ? r : p);
  q += weight;
  c += weight;
  r = fmaxf(1.0f - c, 0.0f);
  cum[tok] = c;
  rem[tok] = r;
  pond[tok] = q;
  wout[tok] = weight;
}

// out (+)= sum_s w_s * h_s   (hi plane only: bf16 precision ample for output)
__global__ __launch_bounds__(256) void act_out_kernel(
    const u16* __restrict__ hbase, size_t pstride, const float* __restrict__ w,
    int nsteps, int accum, float* __restrict__ out, int M) {
  size_t gid = (size_t)blockIdx.x * 256 + threadIdx.x;
  int tok = (int)(gid >> 7);
  int off = ((int)gid & 127) * 8;
  size_t base = (size_t)tok * D_DIM + off;
  float o[8];
  if (accum) {
    float4 a = *(const float4*)(out + base);
    float4 b = *(const float4*)(out + base + 4);
    o[0] = a.x; o[1] = a.y; o[2] = a.z; o[3] = a.w;
    o[4] = b.x; o[5] = b.y; o[6] = b.z; o[7] = b.w;
  } else {
#pragma unroll
    for (int j = 0; j < 8; ++j) o[j] = 0.0f;
  }
  for (int s = 0; s < nsteps; ++s) {
    float ws = w[(size_t)s * M + tok];
    short8 hi = *(const short8*)(hbase + (size_t)s * pstride + base);
#pragma unroll
    for (int j = 0; j < 8; ++j) o[j] += ws * bf2f((u16)hi[j]);
  }
  *(float4*)(out + base) = make_float4(o[0], o[1], o[2], o[3]);
  *(float4*)(out + base + 4) = make_float4(o[4], o[5], o[6], o[7]);
}

__global__ __launch_bounds__(256) void ponder_reduce_kernel(
    const float* __restrict__ pond, float* __restrict__ o, int n) {
  __shared__ float sh[256];
  float a = 0.0f;
  for (int i = threadIdx.x; i < n; i += 256) a += pond[i];
  sh[threadIdx.x] = a;
  __syncthreads();
  for (int s = 128; s; s >>= 1) {
    if ((int)threadIdx.x < s) sh[threadIdx.x] += sh[threadIdx.x + s];
    __syncthreads();
  }
  if (threadIdx.x == 0) o[0] = sh[0] / (float)n;
}

extern "C" void kernel_launch(void* const* d_in, const int* in_sizes, int n_in,
                              void* d_out, int out_size, void* d_ws,
                              size_t ws_size, hipStream_t stream) {
  const float* x = (const float*)d_in[0];
  const float* layer_w = (const float*)d_in[1];
  const float* layer_b = (const float*)d_in[2];
  const float* halt_w = (const float*)d_in[3];
  const float* halt_b = (const float*)d_in[4];
  float* out = (float*)d_out;

  const int D = D_DIM;
  const int M = in_sizes[0] / D;        // 16384
  const int L = in_sizes[1] / (D * D);  // 4
  const size_t MD = (size_t)M * D, DD = (size_t)D * D;

  char* ws = (char*)d_ws;
  size_t off = 0;
  auto alloc = [&](size_t bytes) {
    void* p = ws + off;
    off += (bytes + 255) & ~(size_t)255;
    return p;
  };
  u16* Wsplit = (u16*)alloc((size_t)L * 2 * DD * sizeof(u16));  // hi | lo
  float* zpart = (float*)alloc(4 * (size_t)M * 4);
  float* wbuf = (float*)alloc((size_t)L * M * 4);
  float* cum = (float*)alloc((size_t)M * 4);
  float* rem = (float*)alloc((size_t)M * 4);
  float* pond = (float*)alloc((size_t)M * 4);

  const size_t planeElems = 2 * MD;          // hi + lo (u16)
  const size_t planeBytes = planeElems * 2;  // 67.1 MB
  const bool deferred = (off + (size_t)(L + 1) * planeBytes) <= ws_size;
  const int nbufs = deferred ? (L + 1) : 2;
  u16* planes = (u16*)alloc((size_t)nbufs * planeBytes);

  hipFuncSetAttribute((const void*)gemm_act_kernel,
                      hipFuncAttributeMaxDynamicSharedMemorySize, 131072);

  prep_x_kernel<<<(unsigned)(MD / 1024), 256, 0, stream>>>(x, planes,
                                                           planes + MD);
  prep_w_kernel<<<dim3(D / 64, D / 64, L), 256, 0, stream>>>(
      layer_w, Wsplit, Wsplit + (size_t)L * DD);

  for (int s = 0; s < L; ++s) {
    u16* pin = planes + (size_t)(deferred ? s : (s & 1)) * planeElems;
    u16* pout =
        planes + (size_t)(deferred ? (s + 1) : ((s + 1) & 1)) * planeElems;
    gemm_act_kernel<<<dim3(M / 256 * (D / 256)), 512, 131072, stream>>>(
        pin, pin + MD, Wsplit + (size_t)s * DD, Wsplit + (size_t)(L + s) * DD,
        layer_b + (size_t)s * D, halt_w, pout, pout + MD, zpart, M,
        (s < L - 1) ? 1 : 0);
    act_weights_kernel<<<M / 256, 256, 0, stream>>>(
        zpart, halt_b, cum, rem, pond, wbuf + (size_t)s * M, s,
        (s == L - 1) ? 1 : 0, M, D / 256);
    if (!deferred)
      act_out_kernel<<<(unsigned)(MD / 2048), 256, 0, stream>>>(
          pout, 0, wbuf + (size_t)s * M, 1, (s > 0) ? 1 : 0, out, M);
  }
  if (deferred)
    act_out_kernel<<<(unsigned)(MD / 2048), 256, 0, stream>>>(
        planes + planeElems, planeElems, wbuf, L, 0, out, M);
  ponder_reduce_kernel<<<1, 256, 0, stream>>>(pond, out + MD, M);
}